// Round 9
// baseline (2644.942 us; speedup 1.0000x reference)
//
#include <hip/hip_runtime.h>
#include <math.h>

#define Bn   16
#define Nn   4096
#define Cn   64
#define Mn   1024
#define Kn   32
#define OUTn 128
#define EPS  1e-5f

typedef unsigned long long u64;
typedef unsigned int u32;

__device__ __forceinline__ u64 u64min(u64 a, u64 b) { return a < b ? a : b; }
__device__ __forceinline__ u64 u64max(u64 a, u64 b) { return a > b ? a : b; }

template<int CTRL>
__device__ __forceinline__ u64 dpp_u64(u64 x) {
  union { u64 q; u32 w[2]; } in, out;
  in.q = x;
  out.w[0] = (u32)__builtin_amdgcn_update_dpp((int)in.w[0], (int)in.w[0], CTRL, 0xf, 0xf, false);
  out.w[1] = (u32)__builtin_amdgcn_update_dpp((int)in.w[1], (int)in.w[1], CTRL, 0xf, 0xf, false);
  return out.q;
}

// Canonical GCN wave64 reduce: row_shr 1,2,4,8 -> bcast15 -> bcast31.
// Result valid in lane 63. Pure VALU.
__device__ __forceinline__ u64 wave_max_dpp(u64 v) {
  v = u64max(v, dpp_u64<0x111>(v));
  v = u64max(v, dpp_u64<0x112>(v));
  v = u64max(v, dpp_u64<0x114>(v));
  v = u64max(v, dpp_u64<0x118>(v));
  v = u64max(v, dpp_u64<0x142>(v));
  v = u64max(v, dpp_u64<0x143>(v));
  return v;
}
__device__ __forceinline__ u64 wave_min_dpp(u64 v) {
  v = u64min(v, dpp_u64<0x111>(v));
  v = u64min(v, dpp_u64<0x112>(v));
  v = u64min(v, dpp_u64<0x114>(v));
  v = u64min(v, dpp_u64<0x118>(v));
  v = u64min(v, dpp_u64<0x142>(v));
  v = u64min(v, dpp_u64<0x143>(v));
  return v;
}

// LDS overlay: producer (FPS) arm vs consumer (KNN+MLP) arm. Different blocks
// use different arms; union keeps the block footprint at 65.6 KB -> 2 blocks/CU.
union SmemU {
  struct { float4 pts4[Nn]; u64 pvq[2][4]; } f;
  struct { float A[128][68]; float lnS[2][128]; float lnQ[2][128]; int sel[4][32]; } c;
};

__global__ void init_kernel(int* prog) { prog[threadIdx.x] = 0; }

// ---------------------------------------------------------------------------
// Fused pipeline. Blocks 0..15: FPS producer (r6 structure, 648us measured),
// publishing prog[b]=m+1 (release, agent scope) every 4 steps. Blocks 16..271:
// persistent consumers; consumer r is pinned to batch r&15 and round rt handles
// centroid chunk mc = rt*16 + (r>>4) (4 centroids): spin-wait (acquire) ->
// KNN one-wave-per-centroid -> sel in LDS -> MLP (r8 body) -> store o.
// Co-residency by capacity: 2 blocks/CU (LDS+launch_bounds), 272 << 512 slots.
// ---------------------------------------------------------------------------
__global__ __launch_bounds__(256, 2) void fused_kernel(
    const float* __restrict__ xyz, const float* __restrict__ feat,
    const float* __restrict__ W1, const float* __restrict__ b1,
    const float* __restrict__ g1, const float* __restrict__ be1,
    const float* __restrict__ W2, const float* __restrict__ b2,
    const float* __restrict__ g2, const float* __restrict__ be2,
    const float* __restrict__ Wout, const float* __restrict__ bout,
    float* __restrict__ cent, float* __restrict__ o, int* __restrict__ prog)
{
  __shared__ SmemU sm;
  const int t = threadIdx.x;

  if (blockIdx.x < Bn) {
    // ================= producer: FPS (r6 structure) =================
    const int b = blockIdx.x;
    const float* src = xyz + (size_t)b * Nn * 3;

    for (int i = t; i < Nn; i += 256)
      sm.f.pts4[i] = make_float4(src[3*i+0], src[3*i+1], src[3*i+2], 0.0f);
    __syncthreads();

    const float4 c0 = sm.f.pts4[0];

    float px[16], py[16], pz[16], d[16];
    u32 ninv[16];
#pragma unroll
    for (int j = 0; j < 16; ++j) {
      const int n = j * 256 + t;
      ninv[j] = (u32)(~n);
      const float4 p = sm.f.pts4[n];
      px[j] = p.x; py[j] = p.y; pz[j] = p.z;
      const float dx = px[j] - c0.x, dy = py[j] - c0.y, dz = pz[j] - c0.z;
      d[j] = (dx * dx + dy * dy) + dz * dz;
    }

    if (t == 0) {
      float* oc = cent + (size_t)b * Mn * 3;
      oc[0] = c0.x; oc[1] = c0.y; oc[2] = c0.z;
    }

    for (int m = 1; m < Mn; ++m) {
      u64 k[16];
#pragma unroll
      for (int j = 0; j < 16; ++j)
        k[j] = ((u64)__float_as_uint(d[j]) << 32) | ninv[j];
#pragma unroll
      for (int st = 1; st < 16; st <<= 1)
#pragma unroll
        for (int j = 0; j < 16; j += (st << 1))
          k[j] = u64max(k[j], k[j + st]);

      const u64 bk = wave_max_dpp(k[0]);
      const int par = m & 1;
      if ((t & 63) == 63) sm.f.pvq[par][t >> 6] = bk;
      __syncthreads();

      const u64 f = u64max(u64max(sm.f.pvq[par][0], sm.f.pvq[par][1]),
                           u64max(sm.f.pvq[par][2], sm.f.pvq[par][3]));
      const int fi = (int)(~(u32)f);

      const float4 cp = sm.f.pts4[fi];
      if (t == 0) {
        float* oc = cent + ((size_t)b * Mn + m) * 3;
        oc[0] = cp.x; oc[1] = cp.y; oc[2] = cp.z;
        if ((m & 3) == 3)   // publish chunk completion (orders all prior t==0 stores)
          __hip_atomic_store(prog + b, m + 1, __ATOMIC_RELEASE,
                             __HIP_MEMORY_SCOPE_AGENT);
      }

#pragma unroll
      for (int j = 0; j < 16; ++j) {
        const float dx = px[j] - cp.x, dy = py[j] - cp.y, dz = pz[j] - cp.z;
        const float nd = (dx * dx + dy * dy) + dz * dz;
        d[j] = fminf(d[j], nd);
      }
    }
    return;
  }

  // ================= consumer: KNN + MLP =================
  const int r    = blockIdx.x - Bn;      // 0..255
  const int b    = r & 15;               // pinned batch
  const int lane = t & 63;
  const int wid  = __builtin_amdgcn_readfirstlane(t >> 6);
  const float* P = xyz  + (size_t)b * Nn * 3;
  const float* F = feat + (size_t)b * Nn * Cn;

  for (int rt = 0; rt < 16; ++rt) {
    const int mc   = rt * 16 + (r >> 4);       // chunk 0..255 within batch
    const int g0   = b * Mn + mc * 4;          // first of 4 centroids
    const int need = mc * 4 + 4;

    for (;;) {
      const int v = __hip_atomic_load(prog + b, __ATOMIC_ACQUIRE,
                                      __HIP_MEMORY_SCOPE_AGENT);
      if (v >= need) break;
      __builtin_amdgcn_s_sleep(8);
    }

    // ---- KNN: wave wid -> centroid g0+wid (zero barriers, zero LDS) ----
    {
      const int g = g0 + wid;
      const float cx = cent[(size_t)g * 3 + 0];
      const float cy = cent[(size_t)g * 3 + 1];
      const float cz = cent[(size_t)g * 3 + 2];
      const float cc2 = (cx * cx + cy * cy) + cz * cz;

      u64 kk[4][16];
      u64 gm0, gm1, gm2, gm3;
#pragma unroll
      for (int grp = 0; grp < 4; ++grp) {
#pragma unroll
        for (int j = 0; j < 16; ++j) {
          const int n = grp * 1024 + j * 64 + lane;
          const float x = P[n*3+0], y = P[n*3+1], z = P[n*3+2];
          const float pp = (x * x + y * y) + z * z;
          const float dt = (cx * x + cy * y) + cz * z;
          const float d2 = (cc2 + pp) - 2.0f * dt;
          const u32 bu = __float_as_uint(d2);
          const u32 mo = bu ^ (0x80000000u | (u32)((int)bu >> 31));
          kk[grp][j] = ((u64)mo << 32) | (u32)n;
        }
      }
#define TREE16(dst, A_)                                                 \
      {                                                                 \
        u64 t0 = u64min(A_[0], A_[1]),  t1 = u64min(A_[2], A_[3]);      \
        u64 t2 = u64min(A_[4], A_[5]),  t3 = u64min(A_[6], A_[7]);      \
        u64 t4 = u64min(A_[8], A_[9]),  t5 = u64min(A_[10], A_[11]);    \
        u64 t6 = u64min(A_[12], A_[13]), t7 = u64min(A_[14], A_[15]);   \
        t0 = u64min(t0, t1); t2 = u64min(t2, t3);                       \
        t4 = u64min(t4, t5); t6 = u64min(t6, t7);                       \
        dst = u64min(u64min(t0, t2), u64min(t4, t6));                   \
      }
      TREE16(gm0, kk[0]); TREE16(gm1, kk[1]);
      TREE16(gm2, kk[2]); TREE16(gm3, kk[3]);
      u64 bk = u64min(u64min(gm0, gm1), u64min(gm2, gm3));

      int myfi = 0;
      for (int s = 0; s < Kn; ++s) {
        const u64 v = wave_min_dpp(bk);
        const u32 flo = (u32)__builtin_amdgcn_readlane((int)(u32)v, 63);
        const int fi = (int)flo;
        if (lane == s) myfi = fi;

        const int og = __builtin_amdgcn_readfirstlane(fi >> 10);
        const int oj = __builtin_amdgcn_readfirstlane((fi >> 6) & 15);
        if (lane == (fi & 63)) {
#pragma unroll
          for (int grp = 0; grp < 4; ++grp) {
            if (grp == og) {
#pragma unroll
              for (int j = 0; j < 16; ++j)
                if (j == oj) kk[grp][j] = ~0ull;
              u64 nm;
              TREE16(nm, kk[grp]);
              if (grp == 0) gm0 = nm;
              else if (grp == 1) gm1 = nm;
              else if (grp == 2) gm2 = nm;
              else gm3 = nm;
            }
          }
          bk = u64min(u64min(gm0, gm1), u64min(gm2, gm3));
        }
      }
#undef TREE16
      if (lane < Kn) sm.c.sel[wid][lane] = myfi;
    }
    __syncthreads();

    // ---- MLP for centroids g0..g0+3 (r8 body) ----
    {
      // gather: 2 threads per row
      {
        const int row = t >> 1, half = t & 1;
        const int g = g0 + (row >> 5);
        const int n = sm.c.sel[row >> 5][row & 31];
        const float4* f4 = (const float4*)(F + (size_t)n * Cn + half * 32);
#pragma unroll
        for (int q = 0; q < 8; ++q)
          *(float4*)&sm.c.A[row][half * 32 + q * 4] = f4[q];
        if (half) {
          sm.c.A[row][64] = P[n*3+0] - cent[(size_t)g*3+0];
          sm.c.A[row][65] = P[n*3+1] - cent[(size_t)g*3+1];
          sm.c.A[row][66] = P[n*3+2] - cent[(size_t)g*3+2];
          sm.c.A[row][67] = 0.0f;
        }
      }
      __syncthreads();

      const int row  = ((wid & 1) << 6) + lane;
      const int c0c  = (wid >> 1) << 5;
      const int slot = wid >> 1;

      float x[64];
      float acc[32];

#pragma unroll
      for (int i = 0; i < 16; ++i) {
        const float4 v = *(const float4*)&sm.c.A[row][4 * i];
        x[4*i+0] = v.x; x[4*i+1] = v.y; x[4*i+2] = v.z; x[4*i+3] = v.w;
      }
      const float xc0 = sm.c.A[row][64], xc1 = sm.c.A[row][65], xc2 = sm.c.A[row][66];

      // layer 1 (K=67)
#pragma unroll
      for (int c4 = 0; c4 < 8; ++c4) {
        const int cA = c0c + c4 * 4;
        const float* w0 = W1 + (size_t)(cA + 0) * 67;
        const float* w1 = W1 + (size_t)(cA + 1) * 67;
        const float* w2 = W1 + (size_t)(cA + 2) * 67;
        const float* w3 = W1 + (size_t)(cA + 3) * 67;
        float s0 = fmaf(xc2, w0[2], fmaf(xc1, w0[1], fmaf(xc0, w0[0], b1[cA + 0])));
        float s1 = fmaf(xc2, w1[2], fmaf(xc1, w1[1], fmaf(xc0, w1[0], b1[cA + 1])));
        float s2 = fmaf(xc2, w2[2], fmaf(xc1, w2[1], fmaf(xc0, w2[0], b1[cA + 2])));
        float s3 = fmaf(xc2, w3[2], fmaf(xc1, w3[1], fmaf(xc0, w3[0], b1[cA + 3])));
#pragma unroll
        for (int kq = 0; kq < 64; ++kq) {
          const float xv = x[kq];
          s0 = fmaf(xv, w0[3 + kq], s0);
          s1 = fmaf(xv, w1[3 + kq], s1);
          s2 = fmaf(xv, w2[3 + kq], s2);
          s3 = fmaf(xv, w3[3 + kq], s3);
        }
        acc[c4*4+0] = s0; acc[c4*4+1] = s1; acc[c4*4+2] = s2; acc[c4*4+3] = s3;
      }

      // LN1 + ReLU -> A
      {
        float s = 0.0f, q = 0.0f;
#pragma unroll
        for (int cc = 0; cc < 32; ++cc) { s += acc[cc]; q = fmaf(acc[cc], acc[cc], q); }
        sm.c.lnS[slot][row] = s; sm.c.lnQ[slot][row] = q;
        __syncthreads();
        const float st = s + sm.c.lnS[slot ^ 1][row];
        const float qt = q + sm.c.lnQ[slot ^ 1][row];
        const float mu = st * 0.015625f;
        const float var = qt * 0.015625f - mu * mu;
        const float rs = rsqrtf(var + EPS);
#pragma unroll
        for (int cc = 0; cc < 32; ++cc) {
          const float y = (acc[cc] - mu) * rs * g1[c0c + cc] + be1[c0c + cc];
          acc[cc] = fmaxf(y, 0.0f);
        }
#pragma unroll
        for (int c4 = 0; c4 < 8; ++c4)
          *(float4*)&sm.c.A[row][c0c + c4 * 4] =
              make_float4(acc[c4*4], acc[c4*4+1], acc[c4*4+2], acc[c4*4+3]);
      }
      __syncthreads();

      // layer 2 (K=64)
#pragma unroll
      for (int i = 0; i < 16; ++i) {
        const float4 v = *(const float4*)&sm.c.A[row][4 * i];
        x[4*i+0] = v.x; x[4*i+1] = v.y; x[4*i+2] = v.z; x[4*i+3] = v.w;
      }
#pragma unroll
      for (int c4 = 0; c4 < 8; ++c4) {
        const int cA = c0c + c4 * 4;
        const float* w0 = W2 + (size_t)(cA + 0) * 64;
        const float* w1 = W2 + (size_t)(cA + 1) * 64;
        const float* w2 = W2 + (size_t)(cA + 2) * 64;
        const float* w3 = W2 + (size_t)(cA + 3) * 64;
        float s0 = b2[cA + 0], s1 = b2[cA + 1], s2 = b2[cA + 2], s3 = b2[cA + 3];
#pragma unroll
        for (int kq = 0; kq < 64; ++kq) {
          const float xv = x[kq];
          s0 = fmaf(xv, w0[kq], s0);
          s1 = fmaf(xv, w1[kq], s1);
          s2 = fmaf(xv, w2[kq], s2);
          s3 = fmaf(xv, w3[kq], s3);
        }
        acc[c4*4+0] = s0; acc[c4*4+1] = s1; acc[c4*4+2] = s2; acc[c4*4+3] = s3;
      }

      // LN2 + ReLU -> A
      {
        float s = 0.0f, q = 0.0f;
#pragma unroll
        for (int cc = 0; cc < 32; ++cc) { s += acc[cc]; q = fmaf(acc[cc], acc[cc], q); }
        sm.c.lnS[slot][row] = s; sm.c.lnQ[slot][row] = q;
        __syncthreads();
        const float st = s + sm.c.lnS[slot ^ 1][row];
        const float qt = q + sm.c.lnQ[slot ^ 1][row];
        const float mu = st * 0.015625f;
        const float var = qt * 0.015625f - mu * mu;
        const float rs = rsqrtf(var + EPS);
#pragma unroll
        for (int cc = 0; cc < 32; ++cc) {
          const float y = (acc[cc] - mu) * rs * g2[c0c + cc] + be2[c0c + cc];
          acc[cc] = fmaxf(y, 0.0f);
        }
#pragma unroll
        for (int c4 = 0; c4 < 8; ++c4)
          *(float4*)&sm.c.A[row][c0c + c4 * 4] =
              make_float4(acc[c4*4], acc[c4*4+1], acc[c4*4+2], acc[c4*4+3]);
      }
      __syncthreads();

      // layer 3 (K=64) in two 32-col halves + maxpool + store
#pragma unroll
      for (int i = 0; i < 16; ++i) {
        const float4 v = *(const float4*)&sm.c.A[row][4 * i];
        x[4*i+0] = v.x; x[4*i+1] = v.y; x[4*i+2] = v.z; x[4*i+3] = v.w;
      }
      const int c03 = (wid >> 1) << 6;
      const int g   = g0 + ((wid & 1) << 1) + (lane >> 5);
      float* og = o + (size_t)g * OUTn + c03;

#pragma unroll
      for (int h = 0; h < 2; ++h) {
        const int cb = c03 + h * 32;
#pragma unroll
        for (int c4 = 0; c4 < 8; ++c4) {
          const int cA = cb + c4 * 4;
          const float* w0 = Wout + (size_t)(cA + 0) * 64;
          const float* w1 = Wout + (size_t)(cA + 1) * 64;
          const float* w2 = Wout + (size_t)(cA + 2) * 64;
          const float* w3 = Wout + (size_t)(cA + 3) * 64;
          float s0 = bout[cA + 0], s1 = bout[cA + 1], s2 = bout[cA + 2], s3 = bout[cA + 3];
#pragma unroll
          for (int kq = 0; kq < 64; ++kq) {
            const float xv = x[kq];
            s0 = fmaf(xv, w0[kq], s0);
            s1 = fmaf(xv, w1[kq], s1);
            s2 = fmaf(xv, w2[kq], s2);
            s3 = fmaf(xv, w3[kq], s3);
          }
          acc[c4*4+0] = s0; acc[c4*4+1] = s1; acc[c4*4+2] = s2; acc[c4*4+3] = s3;
        }
#pragma unroll
        for (int cc = 0; cc < 32; ++cc) {
          float v = acc[cc];
          v = fmaxf(v, __shfl_xor(v, 1));
          v = fmaxf(v, __shfl_xor(v, 2));
          v = fmaxf(v, __shfl_xor(v, 4));
          v = fmaxf(v, __shfl_xor(v, 8));
          v = fmaxf(v, __shfl_xor(v, 16));
          acc[cc] = v;
        }
#pragma unroll
        for (int cc = 0; cc < 32; ++cc)
          if ((lane & 31) == cc) og[h * 32 + cc] = acc[cc];
      }
    }
    __syncthreads();    // protect sel/A before next round
  }
}

// ---------------------------------------------------------------------------
extern "C" void kernel_launch(void* const* d_in, const int* in_sizes, int n_in,
                              void* d_out, int out_size, void* d_ws, size_t ws_size,
                              hipStream_t stream)
{
  const float* xyz  = (const float*)d_in[0];
  const float* feat = (const float*)d_in[1];
  const float* W1   = (const float*)d_in[2];
  const float* b1   = (const float*)d_in[3];
  const float* g1   = (const float*)d_in[4];
  const float* be1  = (const float*)d_in[5];
  const float* W2   = (const float*)d_in[6];
  const float* b2   = (const float*)d_in[7];
  const float* g2   = (const float*)d_in[8];
  const float* be2  = (const float*)d_in[9];
  const float* Wout = (const float*)d_in[10];
  const float* bout = (const float*)d_in[11];

  float* outp = (float*)d_out;
  float* cent = outp;                             // (B, M, 3)
  float* o    = outp + (size_t)Bn * Mn * 3;       // (B, M, 128)
  int*   prog = (int*)d_ws;                       // 16 ints

  init_kernel<<<1, Bn, 0, stream>>>(prog);
  fused_kernel<<<Bn + 256, 256, 0, stream>>>(xyz, feat,
                                             W1, b1, g1, be1,
                                             W2, b2, g2, be2,
                                             Wout, bout, cent, o, prog);
}

// Round 10
// 1946.657 us; speedup vs baseline: 1.3587x; 1.3587x over previous
//
#include <hip/hip_runtime.h>
#include <math.h>

#define Bn   16
#define Nn   4096
#define Cn   64
#define Mn   1024
#define Kn   32
#define OUTn 128
#define EPS  1e-5f

typedef unsigned long long u64;
typedef unsigned int u32;

__device__ __forceinline__ u64 u64min(u64 a, u64 b) { return a < b ? a : b; }
__device__ __forceinline__ u64 u64max(u64 a, u64 b) { return a > b ? a : b; }

template<int CTRL>
__device__ __forceinline__ u64 dpp_u64(u64 x) {
  union { u64 q; u32 w[2]; } in, out;
  in.q = x;
  out.w[0] = (u32)__builtin_amdgcn_update_dpp((int)in.w[0], (int)in.w[0], CTRL, 0xf, 0xf, false);
  out.w[1] = (u32)__builtin_amdgcn_update_dpp((int)in.w[1], (int)in.w[1], CTRL, 0xf, 0xf, false);
  return out.q;
}

// Canonical GCN wave64 reduce: row_shr 1,2,4,8 -> bcast15 -> bcast31.
// Result valid in lane 63. Pure VALU.
__device__ __forceinline__ u64 wave_max_dpp(u64 v) {
  v = u64max(v, dpp_u64<0x111>(v));
  v = u64max(v, dpp_u64<0x112>(v));
  v = u64max(v, dpp_u64<0x114>(v));
  v = u64max(v, dpp_u64<0x118>(v));
  v = u64max(v, dpp_u64<0x142>(v));
  v = u64max(v, dpp_u64<0x143>(v));
  return v;
}
__device__ __forceinline__ u64 wave_min_dpp(u64 v) {
  v = u64min(v, dpp_u64<0x111>(v));
  v = u64min(v, dpp_u64<0x112>(v));
  v = u64min(v, dpp_u64<0x114>(v));
  v = u64min(v, dpp_u64<0x118>(v));
  v = u64min(v, dpp_u64<0x142>(v));
  v = u64min(v, dpp_u64<0x143>(v));
  return v;
}

// LDS overlay. Producer arm 48.1 KB (3 scalar point arrays), consumer arm
// 37.4 KB. Union 48.1 KB -> 3 blocks/CU (144 KB < 160 KB).
union SmemU {
  struct { float pxs[Nn], pys[Nn], pzs[Nn]; u64 pvq[2][4]; } f;
  struct { float A[128][68]; float lnS[2][128]; float lnQ[2][128]; int sel[4][32]; } c;
};

__global__ void init_kernel(int* prog) { prog[threadIdx.x] = 0; }

// ---------------------------------------------------------------------------
// Fused pipeline, fixed. Blocks 0..15: FPS producers at s_setprio(3) (protect
// the latency chain from consumer FMA waves sharing the CU); publish
// prog[b]=m+1 (release, agent) every 8 steps. Blocks 16..527: consumers,
// 32/batch x 8 even rounds of 4-centroid chunks; ONLY t==0 polls (acquire +
// s_sleep) -> no coherent-load storm; then KNN (1 wave/centroid) -> sel in
// LDS -> MLP (r8 body) -> store o. 528 blocks <= 768 resident slots (3/CU by
// LDS) -> co-residency by capacity, no deadlock.
// ---------------------------------------------------------------------------
__global__ __launch_bounds__(256, 3) void fused_kernel(
    const float* __restrict__ xyz, const float* __restrict__ feat,
    const float* __restrict__ W1, const float* __restrict__ b1,
    const float* __restrict__ g1, const float* __restrict__ be1,
    const float* __restrict__ W2, const float* __restrict__ b2,
    const float* __restrict__ g2, const float* __restrict__ be2,
    const float* __restrict__ Wout, const float* __restrict__ bout,
    float* __restrict__ cent, float* __restrict__ o, int* __restrict__ prog)
{
  __shared__ SmemU sm;
  const int t = threadIdx.x;

  if (blockIdx.x < Bn) {
    // ================= producer: FPS (r6 structure, scalar pts) ===========
    __builtin_amdgcn_s_setprio(3);
    const int b = blockIdx.x;
    const float* src = xyz + (size_t)b * Nn * 3;

    for (int i = t; i < Nn; i += 256) {
      sm.f.pxs[i] = src[3*i+0];
      sm.f.pys[i] = src[3*i+1];
      sm.f.pzs[i] = src[3*i+2];
    }
    __syncthreads();

    const float c0x = sm.f.pxs[0], c0y = sm.f.pys[0], c0z = sm.f.pzs[0];

    float px[16], py[16], pz[16], d[16];
    u32 ninv[16];
#pragma unroll
    for (int j = 0; j < 16; ++j) {
      const int n = j * 256 + t;
      ninv[j] = (u32)(~n);
      px[j] = sm.f.pxs[n]; py[j] = sm.f.pys[n]; pz[j] = sm.f.pzs[n];
      const float dx = px[j] - c0x, dy = py[j] - c0y, dz = pz[j] - c0z;
      d[j] = (dx * dx + dy * dy) + dz * dz;
    }

    if (t == 0) {
      float* oc = cent + (size_t)b * Mn * 3;
      oc[0] = c0x; oc[1] = c0y; oc[2] = c0z;
    }

    for (int m = 1; m < Mn; ++m) {
      u64 k[16];
#pragma unroll
      for (int j = 0; j < 16; ++j)
        k[j] = ((u64)__float_as_uint(d[j]) << 32) | ninv[j];
#pragma unroll
      for (int st = 1; st < 16; st <<= 1)
#pragma unroll
        for (int j = 0; j < 16; j += (st << 1))
          k[j] = u64max(k[j], k[j + st]);

      const u64 bk = wave_max_dpp(k[0]);
      const int par = m & 1;
      if ((t & 63) == 63) sm.f.pvq[par][t >> 6] = bk;
      __syncthreads();

      const u64 f = u64max(u64max(sm.f.pvq[par][0], sm.f.pvq[par][1]),
                           u64max(sm.f.pvq[par][2], sm.f.pvq[par][3]));
      const int fi = (int)(~(u32)f);

      const float cpx = sm.f.pxs[fi];
      const float cpy = sm.f.pys[fi];
      const float cpz = sm.f.pzs[fi];
      if (t == 0) {
        float* oc = cent + ((size_t)b * Mn + m) * 3;
        oc[0] = cpx; oc[1] = cpy; oc[2] = cpz;
        if ((m & 7) == 7)   // publish (orders all prior t==0 cent stores)
          __hip_atomic_store(prog + b, m + 1, __ATOMIC_RELEASE,
                             __HIP_MEMORY_SCOPE_AGENT);
      }

#pragma unroll
      for (int j = 0; j < 16; ++j) {
        const float dx = px[j] - cpx, dy = py[j] - cpy, dz = pz[j] - cpz;
        const float nd = (dx * dx + dy * dy) + dz * dz;
        d[j] = fminf(d[j], nd);
      }
    }
    return;
  }

  // ================= consumer: KNN + MLP =================
  const int r    = blockIdx.x - Bn;      // 0..511
  const int b    = r & 15;               // pinned batch
  const int slot = r >> 4;               // 0..31
  const int lane = t & 63;
  const int wid  = __builtin_amdgcn_readfirstlane(t >> 6);
  const float* P = xyz  + (size_t)b * Nn * 3;
  const float* F = feat + (size_t)b * Nn * Cn;

  for (int rt = 0; rt < 8; ++rt) {
    const int mc   = rt * 32 + slot;           // chunk 0..255 within batch
    const int g0   = b * Mn + mc * 4;          // first of 4 centroids
    const int need = mc * 4 + 4;

    if (t == 0) {
      while (__hip_atomic_load(prog + b, __ATOMIC_ACQUIRE,
                               __HIP_MEMORY_SCOPE_AGENT) < need)
        __builtin_amdgcn_s_sleep(64);
    }
    __syncthreads();

    // ---- KNN: wave wid -> centroid g0+wid (zero barriers, zero LDS) ----
    {
      const int g = g0 + wid;
      const float cx = cent[(size_t)g * 3 + 0];
      const float cy = cent[(size_t)g * 3 + 1];
      const float cz = cent[(size_t)g * 3 + 2];
      const float cc2 = (cx * cx + cy * cy) + cz * cz;

      u64 kk[4][16];
      u64 gm0, gm1, gm2, gm3;
#pragma unroll
      for (int grp = 0; grp < 4; ++grp) {
#pragma unroll
        for (int j = 0; j < 16; ++j) {
          const int n = grp * 1024 + j * 64 + lane;
          const float x = P[n*3+0], y = P[n*3+1], z = P[n*3+2];
          const float pp = (x * x + y * y) + z * z;
          const float dt = (cx * x + cy * y) + cz * z;
          const float d2 = (cc2 + pp) - 2.0f * dt;
          const u32 bu = __float_as_uint(d2);
          const u32 mo = bu ^ (0x80000000u | (u32)((int)bu >> 31));
          kk[grp][j] = ((u64)mo << 32) | (u32)n;
        }
      }
#define TREE16(dst, A_)                                                 \
      {                                                                 \
        u64 t0 = u64min(A_[0], A_[1]),  t1 = u64min(A_[2], A_[3]);      \
        u64 t2 = u64min(A_[4], A_[5]),  t3 = u64min(A_[6], A_[7]);      \
        u64 t4 = u64min(A_[8], A_[9]),  t5 = u64min(A_[10], A_[11]);    \
        u64 t6 = u64min(A_[12], A_[13]), t7 = u64min(A_[14], A_[15]);   \
        t0 = u64min(t0, t1); t2 = u64min(t2, t3);                       \
        t4 = u64min(t4, t5); t6 = u64min(t6, t7);                       \
        dst = u64min(u64min(t0, t2), u64min(t4, t6));                   \
      }
      TREE16(gm0, kk[0]); TREE16(gm1, kk[1]);
      TREE16(gm2, kk[2]); TREE16(gm3, kk[3]);
      u64 bk = u64min(u64min(gm0, gm1), u64min(gm2, gm3));

      int myfi = 0;
      for (int s = 0; s < Kn; ++s) {
        const u64 v = wave_min_dpp(bk);
        const u32 flo = (u32)__builtin_amdgcn_readlane((int)(u32)v, 63);
        const int fi = (int)flo;
        if (lane == s) myfi = fi;

        const int og = __builtin_amdgcn_readfirstlane(fi >> 10);
        const int oj = __builtin_amdgcn_readfirstlane((fi >> 6) & 15);
        if (lane == (fi & 63)) {
#pragma unroll
          for (int grp = 0; grp < 4; ++grp) {
            if (grp == og) {
#pragma unroll
              for (int j = 0; j < 16; ++j)
                if (j == oj) kk[grp][j] = ~0ull;
              u64 nm;
              TREE16(nm, kk[grp]);
              if (grp == 0) gm0 = nm;
              else if (grp == 1) gm1 = nm;
              else if (grp == 2) gm2 = nm;
              else gm3 = nm;
            }
          }
          bk = u64min(u64min(gm0, gm1), u64min(gm2, gm3));
        }
      }
#undef TREE16
      if (lane < Kn) sm.c.sel[wid][lane] = myfi;
    }
    __syncthreads();

    // ---- MLP for centroids g0..g0+3 (r8 body) ----
    {
      // gather: 2 threads per row
      {
        const int row = t >> 1, half = t & 1;
        const int g = g0 + (row >> 5);
        const int n = sm.c.sel[row >> 5][row & 31];
        const float4* f4 = (const float4*)(F + (size_t)n * Cn + half * 32);
#pragma unroll
        for (int q = 0; q < 8; ++q)
          *(float4*)&sm.c.A[row][half * 32 + q * 4] = f4[q];
        if (half) {
          sm.c.A[row][64] = P[n*3+0] - cent[(size_t)g*3+0];
          sm.c.A[row][65] = P[n*3+1] - cent[(size_t)g*3+1];
          sm.c.A[row][66] = P[n*3+2] - cent[(size_t)g*3+2];
          sm.c.A[row][67] = 0.0f;
        }
      }
      __syncthreads();

      const int row  = ((wid & 1) << 6) + lane;
      const int c0c  = (wid >> 1) << 5;
      const int slot2 = wid >> 1;

      float x[64];
      float acc[32];

#pragma unroll
      for (int i = 0; i < 16; ++i) {
        const float4 v = *(const float4*)&sm.c.A[row][4 * i];
        x[4*i+0] = v.x; x[4*i+1] = v.y; x[4*i+2] = v.z; x[4*i+3] = v.w;
      }
      const float xc0 = sm.c.A[row][64], xc1 = sm.c.A[row][65], xc2 = sm.c.A[row][66];

      // layer 1 (K=67)
#pragma unroll
      for (int c4 = 0; c4 < 8; ++c4) {
        const int cA = c0c + c4 * 4;
        const float* w0 = W1 + (size_t)(cA + 0) * 67;
        const float* w1 = W1 + (size_t)(cA + 1) * 67;
        const float* w2 = W1 + (size_t)(cA + 2) * 67;
        const float* w3 = W1 + (size_t)(cA + 3) * 67;
        float s0 = fmaf(xc2, w0[2], fmaf(xc1, w0[1], fmaf(xc0, w0[0], b1[cA + 0])));
        float s1 = fmaf(xc2, w1[2], fmaf(xc1, w1[1], fmaf(xc0, w1[0], b1[cA + 1])));
        float s2 = fmaf(xc2, w2[2], fmaf(xc1, w2[1], fmaf(xc0, w2[0], b1[cA + 2])));
        float s3 = fmaf(xc2, w3[2], fmaf(xc1, w3[1], fmaf(xc0, w3[0], b1[cA + 3])));
#pragma unroll
        for (int kq = 0; kq < 64; ++kq) {
          const float xv = x[kq];
          s0 = fmaf(xv, w0[3 + kq], s0);
          s1 = fmaf(xv, w1[3 + kq], s1);
          s2 = fmaf(xv, w2[3 + kq], s2);
          s3 = fmaf(xv, w3[3 + kq], s3);
        }
        acc[c4*4+0] = s0; acc[c4*4+1] = s1; acc[c4*4+2] = s2; acc[c4*4+3] = s3;
      }

      // LN1 + ReLU -> A
      {
        float s = 0.0f, q = 0.0f;
#pragma unroll
        for (int cc = 0; cc < 32; ++cc) { s += acc[cc]; q = fmaf(acc[cc], acc[cc], q); }
        sm.c.lnS[slot2][row] = s; sm.c.lnQ[slot2][row] = q;
        __syncthreads();
        const float st = s + sm.c.lnS[slot2 ^ 1][row];
        const float qt = q + sm.c.lnQ[slot2 ^ 1][row];
        const float mu = st * 0.015625f;
        const float var = qt * 0.015625f - mu * mu;
        const float rs = rsqrtf(var + EPS);
#pragma unroll
        for (int cc = 0; cc < 32; ++cc) {
          const float y = (acc[cc] - mu) * rs * g1[c0c + cc] + be1[c0c + cc];
          acc[cc] = fmaxf(y, 0.0f);
        }
#pragma unroll
        for (int c4 = 0; c4 < 8; ++c4)
          *(float4*)&sm.c.A[row][c0c + c4 * 4] =
              make_float4(acc[c4*4], acc[c4*4+1], acc[c4*4+2], acc[c4*4+3]);
      }
      __syncthreads();

      // layer 2 (K=64)
#pragma unroll
      for (int i = 0; i < 16; ++i) {
        const float4 v = *(const float4*)&sm.c.A[row][4 * i];
        x[4*i+0] = v.x; x[4*i+1] = v.y; x[4*i+2] = v.z; x[4*i+3] = v.w;
      }
#pragma unroll
      for (int c4 = 0; c4 < 8; ++c4) {
        const int cA = c0c + c4 * 4;
        const float* w0 = W2 + (size_t)(cA + 0) * 64;
        const float* w1 = W2 + (size_t)(cA + 1) * 64;
        const float* w2 = W2 + (size_t)(cA + 2) * 64;
        const float* w3 = W2 + (size_t)(cA + 3) * 64;
        float s0 = b2[cA + 0], s1 = b2[cA + 1], s2 = b2[cA + 2], s3 = b2[cA + 3];
#pragma unroll
        for (int kq = 0; kq < 64; ++kq) {
          const float xv = x[kq];
          s0 = fmaf(xv, w0[kq], s0);
          s1 = fmaf(xv, w1[kq], s1);
          s2 = fmaf(xv, w2[kq], s2);
          s3 = fmaf(xv, w3[kq], s3);
        }
        acc[c4*4+0] = s0; acc[c4*4+1] = s1; acc[c4*4+2] = s2; acc[c4*4+3] = s3;
      }

      // LN2 + ReLU -> A
      {
        float s = 0.0f, q = 0.0f;
#pragma unroll
        for (int cc = 0; cc < 32; ++cc) { s += acc[cc]; q = fmaf(acc[cc], acc[cc], q); }
        sm.c.lnS[slot2][row] = s; sm.c.lnQ[slot2][row] = q;
        __syncthreads();
        const float st = s + sm.c.lnS[slot2 ^ 1][row];
        const float qt = q + sm.c.lnQ[slot2 ^ 1][row];
        const float mu = st * 0.015625f;
        const float var = qt * 0.015625f - mu * mu;
        const float rs = rsqrtf(var + EPS);
#pragma unroll
        for (int cc = 0; cc < 32; ++cc) {
          const float y = (acc[cc] - mu) * rs * g2[c0c + cc] + be2[c0c + cc];
          acc[cc] = fmaxf(y, 0.0f);
        }
#pragma unroll
        for (int c4 = 0; c4 < 8; ++c4)
          *(float4*)&sm.c.A[row][c0c + c4 * 4] =
              make_float4(acc[c4*4], acc[c4*4+1], acc[c4*4+2], acc[c4*4+3]);
      }
      __syncthreads();

      // layer 3 (K=64) in two 32-col halves + maxpool + store
#pragma unroll
      for (int i = 0; i < 16; ++i) {
        const float4 v = *(const float4*)&sm.c.A[row][4 * i];
        x[4*i+0] = v.x; x[4*i+1] = v.y; x[4*i+2] = v.z; x[4*i+3] = v.w;
      }
      const int c03 = (wid >> 1) << 6;
      const int g   = g0 + ((wid & 1) << 1) + (lane >> 5);
      float* og = o + (size_t)g * OUTn + c03;

#pragma unroll
      for (int h = 0; h < 2; ++h) {
        const int cb = c03 + h * 32;
#pragma unroll
        for (int c4 = 0; c4 < 8; ++c4) {
          const int cA = cb + c4 * 4;
          const float* w0 = Wout + (size_t)(cA + 0) * 64;
          const float* w1 = Wout + (size_t)(cA + 1) * 64;
          const float* w2 = Wout + (size_t)(cA + 2) * 64;
          const float* w3 = Wout + (size_t)(cA + 3) * 64;
          float s0 = bout[cA + 0], s1 = bout[cA + 1], s2 = bout[cA + 2], s3 = bout[cA + 3];
#pragma unroll
          for (int kq = 0; kq < 64; ++kq) {
            const float xv = x[kq];
            s0 = fmaf(xv, w0[kq], s0);
            s1 = fmaf(xv, w1[kq], s1);
            s2 = fmaf(xv, w2[kq], s2);
            s3 = fmaf(xv, w3[kq], s3);
          }
          acc[c4*4+0] = s0; acc[c4*4+1] = s1; acc[c4*4+2] = s2; acc[c4*4+3] = s3;
        }
#pragma unroll
        for (int cc = 0; cc < 32; ++cc) {
          float v = acc[cc];
          v = fmaxf(v, __shfl_xor(v, 1));
          v = fmaxf(v, __shfl_xor(v, 2));
          v = fmaxf(v, __shfl_xor(v, 4));
          v = fmaxf(v, __shfl_xor(v, 8));
          v = fmaxf(v, __shfl_xor(v, 16));
          acc[cc] = v;
        }
#pragma unroll
        for (int cc = 0; cc < 32; ++cc)
          if ((lane & 31) == cc) og[h * 32 + cc] = acc[cc];
      }
    }
    __syncthreads();    // protect sel/A before next round
  }
}

// ---------------------------------------------------------------------------
extern "C" void kernel_launch(void* const* d_in, const int* in_sizes, int n_in,
                              void* d_out, int out_size, void* d_ws, size_t ws_size,
                              hipStream_t stream)
{
  const float* xyz  = (const float*)d_in[0];
  const float* feat = (const float*)d_in[1];
  const float* W1   = (const float*)d_in[2];
  const float* b1   = (const float*)d_in[3];
  const float* g1   = (const float*)d_in[4];
  const float* be1  = (const float*)d_in[5];
  const float* W2   = (const float*)d_in[6];
  const float* b2   = (const float*)d_in[7];
  const float* g2   = (const float*)d_in[8];
  const float* be2  = (const float*)d_in[9];
  const float* Wout = (const float*)d_in[10];
  const float* bout = (const float*)d_in[11];

  float* outp = (float*)d_out;
  float* cent = outp;                             // (B, M, 3)
  float* o    = outp + (size_t)Bn * Mn * 3;       // (B, M, 128)
  int*   prog = (int*)d_ws;                       // 16 ints

  init_kernel<<<1, Bn, 0, stream>>>(prog);
  fused_kernel<<<Bn + 512, 256, 0, stream>>>(xyz, feat,
                                             W1, b1, g1, be1,
                                             W2, b2, g2, be2,
                                             Wout, bout, cent, o, prog);
}

// Round 11
// 1863.865 us; speedup vs baseline: 1.4191x; 1.0444x over previous
//
#include <hip/hip_runtime.h>
#include <math.h>

#define Bn   16
#define Nn   4096
#define Cn   64
#define Mn   1024
#define Kn   32
#define OUTn 128
#define EPS  1e-5f

typedef unsigned long long u64;
typedef unsigned int u32;

__device__ __forceinline__ u64 u64min(u64 a, u64 b) { return a < b ? a : b; }
__device__ __forceinline__ u64 u64max(u64 a, u64 b) { return a > b ? a : b; }

template<int CTRL>
__device__ __forceinline__ u64 dpp_u64(u64 x) {
  union { u64 q; u32 w[2]; } in, out;
  in.q = x;
  out.w[0] = (u32)__builtin_amdgcn_update_dpp((int)in.w[0], (int)in.w[0], CTRL, 0xf, 0xf, false);
  out.w[1] = (u32)__builtin_amdgcn_update_dpp((int)in.w[1], (int)in.w[1], CTRL, 0xf, 0xf, false);
  return out.q;
}

// Canonical GCN wave64 reduce: row_shr 1,2,4,8 -> bcast15 -> bcast31.
// Result valid in lane 63. Pure VALU.
__device__ __forceinline__ u64 wave_max_dpp(u64 v) {
  v = u64max(v, dpp_u64<0x111>(v));
  v = u64max(v, dpp_u64<0x112>(v));
  v = u64max(v, dpp_u64<0x114>(v));
  v = u64max(v, dpp_u64<0x118>(v));
  v = u64max(v, dpp_u64<0x142>(v));
  v = u64max(v, dpp_u64<0x143>(v));
  return v;
}
__device__ __forceinline__ u64 wave_min_dpp(u64 v) {
  v = u64min(v, dpp_u64<0x111>(v));
  v = u64min(v, dpp_u64<0x112>(v));
  v = u64min(v, dpp_u64<0x114>(v));
  v = u64min(v, dpp_u64<0x118>(v));
  v = u64min(v, dpp_u64<0x142>(v));
  v = u64min(v, dpp_u64<0x143>(v));
  return v;
}

// ---------------------------------------------------------------------------
// FPS, 2 independent batches per block (bA = blk, bB = blk+8), 256 threads.
// Each batch follows the r6 structure EXACTLY (bit-identical selection math);
// the two chains interleave so pack/tree/DPP of one fills the dependency
// bubbles of the other, ONE barrier serves both, and the two post-barrier
// combine+centroid LDS reads overlap. 96.2 KB LDS -> 1 block/CU; 8 blocks;
// 1 wave/SIMD -> full VGPR budget, no spill at ~220 VGPRs.
// ---------------------------------------------------------------------------
__global__ __launch_bounds__(256, 1) void fps_kernel(
    const float* __restrict__ xyz, float* __restrict__ cent)
{
  __shared__ float pxsA[Nn], pysA[Nn], pzsA[Nn];
  __shared__ float pxsB[Nn], pysB[Nn], pzsB[Nn];
  __shared__ __align__(16) u64 pvqA[2][4];
  __shared__ __align__(16) u64 pvqB[2][4];

  const int bA = blockIdx.x;
  const int bB = blockIdx.x + 8;
  const int t  = threadIdx.x;
  const float* srcA = xyz + (size_t)bA * Nn * 3;
  const float* srcB = xyz + (size_t)bB * Nn * 3;

  for (int i = t; i < Nn; i += 256) {
    pxsA[i] = srcA[3*i+0]; pysA[i] = srcA[3*i+1]; pzsA[i] = srcA[3*i+2];
    pxsB[i] = srcB[3*i+0]; pysB[i] = srcB[3*i+1]; pzsB[i] = srcB[3*i+2];
  }
  __syncthreads();

  const float c0xA = pxsA[0], c0yA = pysA[0], c0zA = pzsA[0];
  const float c0xB = pxsB[0], c0yB = pysB[0], c0zB = pzsB[0];

  float pxA[16], pyA[16], pzA[16], dA[16];
  float pxB[16], pyB[16], pzB[16], dB[16];
  u32 ninv[16];
#pragma unroll
  for (int j = 0; j < 16; ++j) {
    const int n = j * 256 + t;
    ninv[j] = (u32)(~n);
    pxA[j] = pxsA[n]; pyA[j] = pysA[n]; pzA[j] = pzsA[n];
    {
      const float dx = pxA[j] - c0xA, dy = pyA[j] - c0yA, dz = pzA[j] - c0zA;
      dA[j] = (dx * dx + dy * dy) + dz * dz;
    }
    pxB[j] = pxsB[n]; pyB[j] = pysB[n]; pzB[j] = pzsB[n];
    {
      const float dx = pxB[j] - c0xB, dy = pyB[j] - c0yB, dz = pzB[j] - c0zB;
      dB[j] = (dx * dx + dy * dy) + dz * dz;
    }
  }

  if (t == 0) {
    float* oA = cent + (size_t)bA * Mn * 3;
    oA[0] = c0xA; oA[1] = c0yA; oA[2] = c0zA;
    float* oB = cent + (size_t)bB * Mn * 3;
    oB[0] = c0xB; oB[1] = c0yB; oB[2] = c0zB;
  }

  for (int m = 1; m < Mn; ++m) {
    const int par = m & 1;
    // ---- chain A: pack + tree + DPP ----
    {
      u64 k[16];
#pragma unroll
      for (int j = 0; j < 16; ++j)
        k[j] = ((u64)__float_as_uint(dA[j]) << 32) | ninv[j];
#pragma unroll
      for (int st = 1; st < 16; st <<= 1)
#pragma unroll
        for (int j = 0; j < 16; j += (st << 1))
          k[j] = u64max(k[j], k[j + st]);
      const u64 bk = wave_max_dpp(k[0]);
      if ((t & 63) == 63) pvqA[par][t >> 6] = bk;
    }
    // ---- chain B: pack + tree + DPP ----
    {
      u64 k[16];
#pragma unroll
      for (int j = 0; j < 16; ++j)
        k[j] = ((u64)__float_as_uint(dB[j]) << 32) | ninv[j];
#pragma unroll
      for (int st = 1; st < 16; st <<= 1)
#pragma unroll
        for (int j = 0; j < 16; j += (st << 1))
          k[j] = u64max(k[j], k[j + st]);
      const u64 bk = wave_max_dpp(k[0]);
      if ((t & 63) == 63) pvqB[par][t >> 6] = bk;
    }
    __syncthreads();

    // ---- combine A / B (independent LDS reads overlap) ----
    const u64 fA = u64max(u64max(pvqA[par][0], pvqA[par][1]),
                          u64max(pvqA[par][2], pvqA[par][3]));
    const u64 fB = u64max(u64max(pvqB[par][0], pvqB[par][1]),
                          u64max(pvqB[par][2], pvqB[par][3]));
    const int fiA = (int)(~(u32)fA);
    const int fiB = (int)(~(u32)fB);

    const float cpxA = pxsA[fiA], cpyA = pysA[fiA], cpzA = pzsA[fiA];
    const float cpxB = pxsB[fiB], cpyB = pysB[fiB], cpzB = pzsB[fiB];

    if (t == 0) {
      float* oA = cent + ((size_t)bA * Mn + m) * 3;
      oA[0] = cpxA; oA[1] = cpyA; oA[2] = cpzA;
      float* oB = cent + ((size_t)bB * Mn + m) * 3;
      oB[0] = cpxB; oB[1] = cpyB; oB[2] = cpzB;
    }

#pragma unroll
    for (int j = 0; j < 16; ++j) {
      {
        const float dx = pxA[j] - cpxA, dy = pyA[j] - cpyA, dz = pzA[j] - cpzA;
        const float nd = (dx * dx + dy * dy) + dz * dz;
        dA[j] = fminf(dA[j], nd);
      }
      {
        const float dx = pxB[j] - cpxB, dy = pyB[j] - cpyB, dz = pzB[j] - cpzB;
        const float nd = (dx * dx + dy * dy) + dz * dz;
        dB[j] = fminf(dB[j], nd);
      }
    }
  }
}

// ---------------------------------------------------------------------------
// KNN: ONE WAVE per centroid (4 centroids/block), zero barriers, zero LDS.
// (r8 version, measured fast)
// ---------------------------------------------------------------------------
__global__ __launch_bounds__(256) void knn_kernel(
    const float* __restrict__ xyz, const float* __restrict__ cent,
    int* __restrict__ osel)
{
  const int t    = threadIdx.x;
  const int lane = t & 63;
  const int wid  = __builtin_amdgcn_readfirstlane(t >> 6);
  const int g    = (blockIdx.x << 2) + wid;      // centroid id
  const int b    = g >> 10;
  const float* P = xyz + (size_t)b * Nn * 3;

  const float cx = cent[(size_t)g * 3 + 0];
  const float cy = cent[(size_t)g * 3 + 1];
  const float cz = cent[(size_t)g * 3 + 2];
  const float cc2 = (cx * cx + cy * cy) + cz * cz;

  u64 kk[4][16];
  u64 gm0, gm1, gm2, gm3;

#pragma unroll
  for (int grp = 0; grp < 4; ++grp) {
#pragma unroll
    for (int j = 0; j < 16; ++j) {
      const int n = grp * 1024 + j * 64 + lane;
      const float x = P[n*3+0], y = P[n*3+1], z = P[n*3+2];
      const float pp = (x * x + y * y) + z * z;
      const float dt = (cx * x + cy * y) + cz * z;
      const float d2 = (cc2 + pp) - 2.0f * dt;
      const u32 bu = __float_as_uint(d2);
      const u32 mo = bu ^ (0x80000000u | (u32)((int)bu >> 31)); // order-preserving
      kk[grp][j] = ((u64)mo << 32) | (u32)n;
    }
  }
#define TREE16(dst, A_)                                                 \
  {                                                                     \
    u64 t0 = u64min(A_[0], A_[1]),  t1 = u64min(A_[2], A_[3]);          \
    u64 t2 = u64min(A_[4], A_[5]),  t3 = u64min(A_[6], A_[7]);          \
    u64 t4 = u64min(A_[8], A_[9]),  t5 = u64min(A_[10], A_[11]);        \
    u64 t6 = u64min(A_[12], A_[13]), t7 = u64min(A_[14], A_[15]);       \
    t0 = u64min(t0, t1); t2 = u64min(t2, t3);                           \
    t4 = u64min(t4, t5); t6 = u64min(t6, t7);                           \
    dst = u64min(u64min(t0, t2), u64min(t4, t6));                       \
  }
  TREE16(gm0, kk[0]); TREE16(gm1, kk[1]);
  TREE16(gm2, kk[2]); TREE16(gm3, kk[3]);
  u64 bk = u64min(u64min(gm0, gm1), u64min(gm2, gm3));

  int myfi = 0;
  for (int s = 0; s < Kn; ++s) {
    const u64 v = wave_min_dpp(bk);
    const u32 flo = (u32)__builtin_amdgcn_readlane((int)(u32)v, 63);
    const int fi = (int)flo;                       // point index (uniform)
    if (lane == s) myfi = fi;

    const int og = __builtin_amdgcn_readfirstlane(fi >> 10);       // group
    const int oj = __builtin_amdgcn_readfirstlane((fi >> 6) & 15); // slot
    if (lane == (fi & 63)) {                       // unique owner lane
#pragma unroll
      for (int grp = 0; grp < 4; ++grp) {
        if (grp == og) {
#pragma unroll
          for (int j = 0; j < 16; ++j)
            if (j == oj) kk[grp][j] = ~0ull;
          u64 nm;
          TREE16(nm, kk[grp]);
          if (grp == 0) gm0 = nm;
          else if (grp == 1) gm1 = nm;
          else if (grp == 2) gm2 = nm;
          else gm3 = nm;
        }
      }
      bk = u64min(u64min(gm0, gm1), u64min(gm2, gm3));
    }
  }
#undef TREE16

  if (lane < Kn) osel[(size_t)g * 128 + lane] = myfi;
}

// ---------------------------------------------------------------------------
// MLP: one block (256 thr) per 4 centroids = 128 rows. (r8 version)
// Row hoisted to 64 VGPRs per layer; cc-outer jammed x4 over contiguous
// weight rows. Layer 3 in two 32-col halves. LN via cross-wave LDS exchange.
// ---------------------------------------------------------------------------
__global__ __launch_bounds__(256) void mlp_kernel(
    const float* __restrict__ xyz, const float* __restrict__ feat,
    const float* __restrict__ W1, const float* __restrict__ b1,
    const float* __restrict__ g1, const float* __restrict__ be1,
    const float* __restrict__ W2, const float* __restrict__ b2,
    const float* __restrict__ g2, const float* __restrict__ be2,
    const float* __restrict__ Wout, const float* __restrict__ bout,
    const float* __restrict__ cent, float* __restrict__ out)
{
  __shared__ float A[128][68];
  __shared__ float lnS[2][128];
  __shared__ float lnQ[2][128];

  const int bm0 = blockIdx.x << 2;
  const int b   = bm0 >> 10;
  const int t   = threadIdx.x;
  const int wid = __builtin_amdgcn_readfirstlane(t >> 6);
  const int lane = t & 63;

  const float* F = feat + (size_t)b * Nn * Cn;
  const float* P = xyz  + (size_t)b * Nn * 3;
  const int* osel = (const int*)out;

  // ---- gather: 2 threads per row ----
  {
    const int row = t >> 1, half = t & 1;
    const int g = bm0 + (row >> 5);
    const int n = osel[(size_t)g * 128 + (row & 31)];
    const float4* f4 = (const float4*)(F + (size_t)n * Cn + half * 32);
#pragma unroll
    for (int q = 0; q < 8; ++q)
      *(float4*)&A[row][half * 32 + q * 4] = f4[q];
    if (half) {
      A[row][64] = P[n*3+0] - cent[(size_t)g*3+0];
      A[row][65] = P[n*3+1] - cent[(size_t)g*3+1];
      A[row][66] = P[n*3+2] - cent[(size_t)g*3+2];
      A[row][67] = 0.0f;
    }
  }
  __syncthreads();

  const int row  = ((wid & 1) << 6) + lane;
  const int c0   = (wid >> 1) << 5;
  const int slot = wid >> 1;

  float x[64];
  float acc[32];

#pragma unroll
  for (int i = 0; i < 16; ++i) {
    const float4 v = *(const float4*)&A[row][4 * i];
    x[4*i+0] = v.x; x[4*i+1] = v.y; x[4*i+2] = v.z; x[4*i+3] = v.w;
  }
  const float xc0 = A[row][64], xc1 = A[row][65], xc2 = A[row][66];

  // ---- layer 1 (K=67) ----
#pragma unroll
  for (int c4 = 0; c4 < 8; ++c4) {
    const int cA = c0 + c4 * 4;
    const float* w0 = W1 + (size_t)(cA + 0) * 67;
    const float* w1 = W1 + (size_t)(cA + 1) * 67;
    const float* w2 = W1 + (size_t)(cA + 2) * 67;
    const float* w3 = W1 + (size_t)(cA + 3) * 67;
    float s0 = fmaf(xc2, w0[2], fmaf(xc1, w0[1], fmaf(xc0, w0[0], b1[cA + 0])));
    float s1 = fmaf(xc2, w1[2], fmaf(xc1, w1[1], fmaf(xc0, w1[0], b1[cA + 1])));
    float s2 = fmaf(xc2, w2[2], fmaf(xc1, w2[1], fmaf(xc0, w2[0], b1[cA + 2])));
    float s3 = fmaf(xc2, w3[2], fmaf(xc1, w3[1], fmaf(xc0, w3[0], b1[cA + 3])));
#pragma unroll
    for (int kq = 0; kq < 64; ++kq) {
      const float xv = x[kq];
      s0 = fmaf(xv, w0[3 + kq], s0);
      s1 = fmaf(xv, w1[3 + kq], s1);
      s2 = fmaf(xv, w2[3 + kq], s2);
      s3 = fmaf(xv, w3[3 + kq], s3);
    }
    acc[c4*4+0] = s0; acc[c4*4+1] = s1; acc[c4*4+2] = s2; acc[c4*4+3] = s3;
  }

  // ---- LN1 + ReLU -> A ----
  {
    float s = 0.0f, q = 0.0f;
#pragma unroll
    for (int cc = 0; cc < 32; ++cc) { s += acc[cc]; q = fmaf(acc[cc], acc[cc], q); }
    lnS[slot][row] = s; lnQ[slot][row] = q;
    __syncthreads();
    const float st = s + lnS[slot ^ 1][row];
    const float qt = q + lnQ[slot ^ 1][row];
    const float mu = st * 0.015625f;
    const float var = qt * 0.015625f - mu * mu;
    const float rs = rsqrtf(var + EPS);
#pragma unroll
    for (int cc = 0; cc < 32; ++cc) {
      const float y = (acc[cc] - mu) * rs * g1[c0 + cc] + be1[c0 + cc];
      acc[cc] = fmaxf(y, 0.0f);
    }
#pragma unroll
    for (int c4 = 0; c4 < 8; ++c4)
      *(float4*)&A[row][c0 + c4 * 4] =
          make_float4(acc[c4*4], acc[c4*4+1], acc[c4*4+2], acc[c4*4+3]);
  }
  __syncthreads();

  // ---- layer 2 (K=64) ----
#pragma unroll
  for (int i = 0; i < 16; ++i) {
    const float4 v = *(const float4*)&A[row][4 * i];
    x[4*i+0] = v.x; x[4*i+1] = v.y; x[4*i+2] = v.z; x[4*i+3] = v.w;
  }
#pragma unroll
  for (int c4 = 0; c4 < 8; ++c4) {
    const int cA = c0 + c4 * 4;
    const float* w0 = W2 + (size_t)(cA + 0) * 64;
    const float* w1 = W2 + (size_t)(cA + 1) * 64;
    const float* w2 = W2 + (size_t)(cA + 2) * 64;
    const float* w3 = W2 + (size_t)(cA + 3) * 64;
    float s0 = b2[cA + 0], s1 = b2[cA + 1], s2 = b2[cA + 2], s3 = b2[cA + 3];
#pragma unroll
    for (int kq = 0; kq < 64; ++kq) {
      const float xv = x[kq];
      s0 = fmaf(xv, w0[kq], s0);
      s1 = fmaf(xv, w1[kq], s1);
      s2 = fmaf(xv, w2[kq], s2);
      s3 = fmaf(xv, w3[kq], s3);
    }
    acc[c4*4+0] = s0; acc[c4*4+1] = s1; acc[c4*4+2] = s2; acc[c4*4+3] = s3;
  }

  // ---- LN2 + ReLU -> A ----
  {
    float s = 0.0f, q = 0.0f;
#pragma unroll
    for (int cc = 0; cc < 32; ++cc) { s += acc[cc]; q = fmaf(acc[cc], acc[cc], q); }
    lnS[slot][row] = s; lnQ[slot][row] = q;
    __syncthreads();
    const float st = s + lnS[slot ^ 1][row];
    const float qt = q + lnQ[slot ^ 1][row];
    const float mu = st * 0.015625f;
    const float var = qt * 0.015625f - mu * mu;
    const float rs = rsqrtf(var + EPS);
#pragma unroll
    for (int cc = 0; cc < 32; ++cc) {
      const float y = (acc[cc] - mu) * rs * g2[c0 + cc] + be2[c0 + cc];
      acc[cc] = fmaxf(y, 0.0f);
    }
#pragma unroll
    for (int c4 = 0; c4 < 8; ++c4)
      *(float4*)&A[row][c0 + c4 * 4] =
          make_float4(acc[c4*4], acc[c4*4+1], acc[c4*4+2], acc[c4*4+3]);
  }
  __syncthreads();

  // ---- layer 3 (K=64) in two 32-col halves + maxpool + store ----
#pragma unroll
  for (int i = 0; i < 16; ++i) {
    const float4 v = *(const float4*)&A[row][4 * i];
    x[4*i+0] = v.x; x[4*i+1] = v.y; x[4*i+2] = v.z; x[4*i+3] = v.w;
  }
  const int c03 = (wid >> 1) << 6;
  const int g   = bm0 + ((wid & 1) << 1) + (lane >> 5);
  float* og = out + (size_t)g * OUTn + c03;

#pragma unroll
  for (int h = 0; h < 2; ++h) {
    const int cb = c03 + h * 32;
#pragma unroll
    for (int c4 = 0; c4 < 8; ++c4) {
      const int cA = cb + c4 * 4;
      const float* w0 = Wout + (size_t)(cA + 0) * 64;
      const float* w1 = Wout + (size_t)(cA + 1) * 64;
      const float* w2 = Wout + (size_t)(cA + 2) * 64;
      const float* w3 = Wout + (size_t)(cA + 3) * 64;
      float s0 = bout[cA + 0], s1 = bout[cA + 1], s2 = bout[cA + 2], s3 = bout[cA + 3];
#pragma unroll
      for (int kq = 0; kq < 64; ++kq) {
        const float xv = x[kq];
        s0 = fmaf(xv, w0[kq], s0);
        s1 = fmaf(xv, w1[kq], s1);
        s2 = fmaf(xv, w2[kq], s2);
        s3 = fmaf(xv, w3[kq], s3);
      }
      acc[c4*4+0] = s0; acc[c4*4+1] = s1; acc[c4*4+2] = s2; acc[c4*4+3] = s3;
    }
#pragma unroll
    for (int cc = 0; cc < 32; ++cc) {
      float v = acc[cc];
      v = fmaxf(v, __shfl_xor(v, 1));
      v = fmaxf(v, __shfl_xor(v, 2));
      v = fmaxf(v, __shfl_xor(v, 4));
      v = fmaxf(v, __shfl_xor(v, 8));
      v = fmaxf(v, __shfl_xor(v, 16));
      acc[cc] = v;
    }
#pragma unroll
    for (int cc = 0; cc < 32; ++cc)
      if ((lane & 31) == cc) og[h * 32 + cc] = acc[cc];
  }
}

// ---------------------------------------------------------------------------
extern "C" void kernel_launch(void* const* d_in, const int* in_sizes, int n_in,
                              void* d_out, int out_size, void* d_ws, size_t ws_size,
                              hipStream_t stream)
{
  const float* xyz  = (const float*)d_in[0];
  const float* feat = (const float*)d_in[1];
  const float* W1   = (const float*)d_in[2];
  const float* b1   = (const float*)d_in[3];
  const float* g1   = (const float*)d_in[4];
  const float* be1  = (const float*)d_in[5];
  const float* W2   = (const float*)d_in[6];
  const float* b2   = (const float*)d_in[7];
  const float* g2   = (const float*)d_in[8];
  const float* be2  = (const float*)d_in[9];
  const float* Wout = (const float*)d_in[10];
  const float* bout = (const float*)d_in[11];

  float* outp = (float*)d_out;
  float* cent = outp;                             // (B, M, 3)
  float* o    = outp + (size_t)Bn * Mn * 3;       // (B, M, 128)

  fps_kernel<<<Bn / 2, 256, 0, stream>>>(xyz, cent);
  knn_kernel<<<Bn * Mn / 4, 256, 0, stream>>>(xyz, cent, (int*)o);
  mlp_kernel<<<Bn * Mn / 4, 256, 0, stream>>>(xyz, feat,
                                              W1, b1, g1, be1,
                                              W2, b2, g2, be2,
                                              Wout, bout, cent, o);
}

// Round 12
// 1351.498 us; speedup vs baseline: 1.9570x; 1.3791x over previous
//
#include <hip/hip_runtime.h>
#include <math.h>

#define Bn   16
#define Nn   4096
#define Cn   64
#define Mn   1024
#define Kn   32
#define OUTn 128
#define EPS  1e-5f

typedef unsigned long long u64;
typedef unsigned int u32;

__device__ __forceinline__ u64 u64min(u64 a, u64 b) { return a < b ? a : b; }
__device__ __forceinline__ u64 u64max(u64 a, u64 b) { return a > b ? a : b; }

template<int CTRL>
__device__ __forceinline__ u64 dpp_u64(u64 x) {
  union { u64 q; u32 w[2]; } in, out;
  in.q = x;
  out.w[0] = (u32)__builtin_amdgcn_update_dpp((int)in.w[0], (int)in.w[0], CTRL, 0xf, 0xf, false);
  out.w[1] = (u32)__builtin_amdgcn_update_dpp((int)in.w[1], (int)in.w[1], CTRL, 0xf, 0xf, false);
  return out.q;
}

// Canonical GCN wave64 reduce: row_shr 1,2,4,8 -> bcast15 -> bcast31.
// Result valid in lane 63. Pure VALU.
__device__ __forceinline__ u64 wave_max_dpp(u64 v) {
  v = u64max(v, dpp_u64<0x111>(v));
  v = u64max(v, dpp_u64<0x112>(v));
  v = u64max(v, dpp_u64<0x114>(v));
  v = u64max(v, dpp_u64<0x118>(v));
  v = u64max(v, dpp_u64<0x142>(v));
  v = u64max(v, dpp_u64<0x143>(v));
  return v;
}
__device__ __forceinline__ u64 wave_min_dpp(u64 v) {
  v = u64min(v, dpp_u64<0x111>(v));
  v = u64min(v, dpp_u64<0x112>(v));
  v = u64min(v, dpp_u64<0x114>(v));
  v = u64min(v, dpp_u64<0x118>(v));
  v = u64min(v, dpp_u64<0x142>(v));
  v = u64min(v, dpp_u64<0x143>(v));
  return v;
}

// ---------------------------------------------------------------------------
// FPS: byte-exact r6 structure (best measured: 648 us). One block/batch,
// 256 threads, 16 pts/thread in regs. Keys (bits(d)<<32)|~n; u64 MAX ==
// (max d, tie -> lowest n) == jnp.argmax first-max semantics. Per step:
// pack + depth-4 tree + DPP wave reduce (lane63) -> 4-partial LDS combine
// (parity buffers, ONE barrier) -> b128 centroid read.
// ---------------------------------------------------------------------------
__global__ __launch_bounds__(256) void fps_kernel(
    const float* __restrict__ xyz, float* __restrict__ cent)
{
  __shared__ float4 pts4[Nn];          // 64 KB
  __shared__ __align__(16) u64 pvq[2][4];

  const int b = blockIdx.x;
  const int t = threadIdx.x;
  const float* src = xyz + (size_t)b * Nn * 3;

  for (int i = t; i < Nn; i += 256) {
    pts4[i] = make_float4(src[3*i+0], src[3*i+1], src[3*i+2], 0.0f);
  }
  __syncthreads();

  const float4 c0 = pts4[0];

  float px[16], py[16], pz[16], d[16];
  u32 ninv[16];
#pragma unroll
  for (int j = 0; j < 16; ++j) {
    const int n = j * 256 + t;
    ninv[j] = (u32)(~n);
    const float4 p = pts4[n];
    px[j] = p.x; py[j] = p.y; pz[j] = p.z;
    const float dx = px[j] - c0.x, dy = py[j] - c0.y, dz = pz[j] - c0.z;
    d[j] = (dx * dx + dy * dy) + dz * dz;
  }

  if (t == 0) {
    float* o = cent + (size_t)b * Mn * 3;
    o[0] = c0.x; o[1] = c0.y; o[2] = c0.z;
  }

  for (int m = 1; m < Mn; ++m) {
    u64 k[16];
#pragma unroll
    for (int j = 0; j < 16; ++j)
      k[j] = ((u64)__float_as_uint(d[j]) << 32) | ninv[j];
#pragma unroll
    for (int st = 1; st < 16; st <<= 1)
#pragma unroll
      for (int j = 0; j < 16; j += (st << 1))
        k[j] = u64max(k[j], k[j + st]);

    const u64 bk = wave_max_dpp(k[0]);
    const int par = m & 1;
    if ((t & 63) == 63) pvq[par][t >> 6] = bk;
    __syncthreads();

    const u64 f = u64max(u64max(pvq[par][0], pvq[par][1]),
                         u64max(pvq[par][2], pvq[par][3]));
    const int fi = (int)(~(u32)f);      // low word was ~n

    const float4 cp = pts4[fi];
    if (t == 0) {
      float* o = cent + ((size_t)b * Mn + m) * 3;
      o[0] = cp.x; o[1] = cp.y; o[2] = cp.z;
    }

#pragma unroll
    for (int j = 0; j < 16; ++j) {
      const float dx = px[j] - cp.x, dy = py[j] - cp.y, dz = pz[j] - cp.z;
      const float nd = (dx * dx + dy * dy) + dz * dz;
      d[j] = fminf(d[j], nd);
    }
  }
}

// ---------------------------------------------------------------------------
// Fused KNN + MLP: one block (256 thr) per 4 centroids. KNN phase: one wave
// per centroid (r8 logic, zero barriers) -> sel in LDS. MLP phase: r8 body
// (row in 64 VGPRs, cc-outer x4 jam, LN via cross-wave LDS exchange,
// layer 3 in two 32-col halves + shfl maxpool). Saves the osel global
// round-trip and one launch vs the split version.
// ---------------------------------------------------------------------------
__global__ __launch_bounds__(256) void sa2_kernel(
    const float* __restrict__ xyz, const float* __restrict__ feat,
    const float* __restrict__ W1, const float* __restrict__ b1,
    const float* __restrict__ g1, const float* __restrict__ be1,
    const float* __restrict__ W2, const float* __restrict__ b2,
    const float* __restrict__ g2, const float* __restrict__ be2,
    const float* __restrict__ Wout, const float* __restrict__ bout,
    const float* __restrict__ cent, float* __restrict__ out)
{
  __shared__ float A[128][68];
  __shared__ float lnS[2][128];
  __shared__ float lnQ[2][128];
  __shared__ int   sel[4][32];

  const int g0   = blockIdx.x << 2;          // 4 centroids (same batch; 1024%4==0)
  const int b    = g0 >> 10;
  const int t    = threadIdx.x;
  const int wid  = __builtin_amdgcn_readfirstlane(t >> 6);
  const int lane = t & 63;

  const float* P = xyz  + (size_t)b * Nn * 3;
  const float* F = feat + (size_t)b * Nn * Cn;

  // ================= KNN: wave wid -> centroid g0+wid =================
  {
    const int g = g0 + wid;
    const float cx = cent[(size_t)g * 3 + 0];
    const float cy = cent[(size_t)g * 3 + 1];
    const float cz = cent[(size_t)g * 3 + 2];
    const float cc2 = (cx * cx + cy * cy) + cz * cz;

    u64 kk[4][16];
    u64 gm0, gm1, gm2, gm3;
#pragma unroll
    for (int grp = 0; grp < 4; ++grp) {
#pragma unroll
      for (int j = 0; j < 16; ++j) {
        const int n = grp * 1024 + j * 64 + lane;
        const float x = P[n*3+0], y = P[n*3+1], z = P[n*3+2];
        const float pp = (x * x + y * y) + z * z;
        const float dt = (cx * x + cy * y) + cz * z;
        const float d2 = (cc2 + pp) - 2.0f * dt;
        const u32 bu = __float_as_uint(d2);
        const u32 mo = bu ^ (0x80000000u | (u32)((int)bu >> 31)); // order-preserving
        kk[grp][j] = ((u64)mo << 32) | (u32)n;
      }
    }
#define TREE16(dst, A_)                                                 \
    {                                                                   \
      u64 t0 = u64min(A_[0], A_[1]),  t1 = u64min(A_[2], A_[3]);        \
      u64 t2 = u64min(A_[4], A_[5]),  t3 = u64min(A_[6], A_[7]);        \
      u64 t4 = u64min(A_[8], A_[9]),  t5 = u64min(A_[10], A_[11]);      \
      u64 t6 = u64min(A_[12], A_[13]), t7 = u64min(A_[14], A_[15]);     \
      t0 = u64min(t0, t1); t2 = u64min(t2, t3);                         \
      t4 = u64min(t4, t5); t6 = u64min(t6, t7);                         \
      dst = u64min(u64min(t0, t2), u64min(t4, t6));                     \
    }
    TREE16(gm0, kk[0]); TREE16(gm1, kk[1]);
    TREE16(gm2, kk[2]); TREE16(gm3, kk[3]);
    u64 bk = u64min(u64min(gm0, gm1), u64min(gm2, gm3));

    int myfi = 0;
    for (int s = 0; s < Kn; ++s) {
      const u64 v = wave_min_dpp(bk);
      const u32 flo = (u32)__builtin_amdgcn_readlane((int)(u32)v, 63);
      const int fi = (int)flo;                       // point index (uniform)
      if (lane == s) myfi = fi;

      const int og = __builtin_amdgcn_readfirstlane(fi >> 10);       // group
      const int oj = __builtin_amdgcn_readfirstlane((fi >> 6) & 15); // slot
      if (lane == (fi & 63)) {                       // unique owner lane
#pragma unroll
        for (int grp = 0; grp < 4; ++grp) {
          if (grp == og) {
#pragma unroll
            for (int j = 0; j < 16; ++j)
              if (j == oj) kk[grp][j] = ~0ull;
            u64 nm;
            TREE16(nm, kk[grp]);
            if (grp == 0) gm0 = nm;
            else if (grp == 1) gm1 = nm;
            else if (grp == 2) gm2 = nm;
            else gm3 = nm;
          }
        }
        bk = u64min(u64min(gm0, gm1), u64min(gm2, gm3));
      }
    }
#undef TREE16
    if (lane < Kn) sel[wid][lane] = myfi;
  }
  __syncthreads();

  // ================= MLP (r8 body) =================
  // gather: 2 threads per row
  {
    const int row = t >> 1, half = t & 1;
    const int g = g0 + (row >> 5);
    const int n = sel[row >> 5][row & 31];
    const float4* f4 = (const float4*)(F + (size_t)n * Cn + half * 32);
#pragma unroll
    for (int q = 0; q < 8; ++q)
      *(float4*)&A[row][half * 32 + q * 4] = f4[q];
    if (half) {
      A[row][64] = P[n*3+0] - cent[(size_t)g*3+0];
      A[row][65] = P[n*3+1] - cent[(size_t)g*3+1];
      A[row][66] = P[n*3+2] - cent[(size_t)g*3+2];
      A[row][67] = 0.0f;
    }
  }
  __syncthreads();

  const int row  = ((wid & 1) << 6) + lane;
  const int c0   = (wid >> 1) << 5;
  const int slot = wid >> 1;

  float x[64];
  float acc[32];

#pragma unroll
  for (int i = 0; i < 16; ++i) {
    const float4 v = *(const float4*)&A[row][4 * i];
    x[4*i+0] = v.x; x[4*i+1] = v.y; x[4*i+2] = v.z; x[4*i+3] = v.w;
  }
  const float xc0 = A[row][64], xc1 = A[row][65], xc2 = A[row][66];

  // layer 1 (K=67): X cols 0..63 -> W1 cols 3..66; coords -> W1 0..2
#pragma unroll
  for (int c4 = 0; c4 < 8; ++c4) {
    const int cA = c0 + c4 * 4;
    const float* w0 = W1 + (size_t)(cA + 0) * 67;
    const float* w1 = W1 + (size_t)(cA + 1) * 67;
    const float* w2 = W1 + (size_t)(cA + 2) * 67;
    const float* w3 = W1 + (size_t)(cA + 3) * 67;
    float s0 = fmaf(xc2, w0[2], fmaf(xc1, w0[1], fmaf(xc0, w0[0], b1[cA + 0])));
    float s1 = fmaf(xc2, w1[2], fmaf(xc1, w1[1], fmaf(xc0, w1[0], b1[cA + 1])));
    float s2 = fmaf(xc2, w2[2], fmaf(xc1, w2[1], fmaf(xc0, w2[0], b1[cA + 2])));
    float s3 = fmaf(xc2, w3[2], fmaf(xc1, w3[1], fmaf(xc0, w3[0], b1[cA + 3])));
#pragma unroll
    for (int kq = 0; kq < 64; ++kq) {
      const float xv = x[kq];
      s0 = fmaf(xv, w0[3 + kq], s0);
      s1 = fmaf(xv, w1[3 + kq], s1);
      s2 = fmaf(xv, w2[3 + kq], s2);
      s3 = fmaf(xv, w3[3 + kq], s3);
    }
    acc[c4*4+0] = s0; acc[c4*4+1] = s1; acc[c4*4+2] = s2; acc[c4*4+3] = s3;
  }

  // LN1 + ReLU -> A
  {
    float s = 0.0f, q = 0.0f;
#pragma unroll
    for (int cc = 0; cc < 32; ++cc) { s += acc[cc]; q = fmaf(acc[cc], acc[cc], q); }
    lnS[slot][row] = s; lnQ[slot][row] = q;
    __syncthreads();
    const float st = s + lnS[slot ^ 1][row];
    const float qt = q + lnQ[slot ^ 1][row];
    const float mu = st * 0.015625f;
    const float var = qt * 0.015625f - mu * mu;
    const float rs = rsqrtf(var + EPS);
#pragma unroll
    for (int cc = 0; cc < 32; ++cc) {
      const float y = (acc[cc] - mu) * rs * g1[c0 + cc] + be1[c0 + cc];
      acc[cc] = fmaxf(y, 0.0f);
    }
#pragma unroll
    for (int c4 = 0; c4 < 8; ++c4)
      *(float4*)&A[row][c0 + c4 * 4] =
          make_float4(acc[c4*4], acc[c4*4+1], acc[c4*4+2], acc[c4*4+3]);
  }
  __syncthreads();

  // layer 2 (K=64)
#pragma unroll
  for (int i = 0; i < 16; ++i) {
    const float4 v = *(const float4*)&A[row][4 * i];
    x[4*i+0] = v.x; x[4*i+1] = v.y; x[4*i+2] = v.z; x[4*i+3] = v.w;
  }
#pragma unroll
  for (int c4 = 0; c4 < 8; ++c4) {
    const int cA = c0 + c4 * 4;
    const float* w0 = W2 + (size_t)(cA + 0) * 64;
    const float* w1 = W2 + (size_t)(cA + 1) * 64;
    const float* w2 = W2 + (size_t)(cA + 2) * 64;
    const float* w3 = W2 + (size_t)(cA + 3) * 64;
    float s0 = b2[cA + 0], s1 = b2[cA + 1], s2 = b2[cA + 2], s3 = b2[cA + 3];
#pragma unroll
    for (int kq = 0; kq < 64; ++kq) {
      const float xv = x[kq];
      s0 = fmaf(xv, w0[kq], s0);
      s1 = fmaf(xv, w1[kq], s1);
      s2 = fmaf(xv, w2[kq], s2);
      s3 = fmaf(xv, w3[kq], s3);
    }
    acc[c4*4+0] = s0; acc[c4*4+1] = s1; acc[c4*4+2] = s2; acc[c4*4+3] = s3;
  }

  // LN2 + ReLU -> A
  {
    float s = 0.0f, q = 0.0f;
#pragma unroll
    for (int cc = 0; cc < 32; ++cc) { s += acc[cc]; q = fmaf(acc[cc], acc[cc], q); }
    lnS[slot][row] = s; lnQ[slot][row] = q;
    __syncthreads();
    const float st = s + lnS[slot ^ 1][row];
    const float qt = q + lnQ[slot ^ 1][row];
    const float mu = st * 0.015625f;
    const float var = qt * 0.015625f - mu * mu;
    const float rs = rsqrtf(var + EPS);
#pragma unroll
    for (int cc = 0; cc < 32; ++cc) {
      const float y = (acc[cc] - mu) * rs * g2[c0 + cc] + be2[c0 + cc];
      acc[cc] = fmaxf(y, 0.0f);
    }
#pragma unroll
    for (int c4 = 0; c4 < 8; ++c4)
      *(float4*)&A[row][c0 + c4 * 4] =
          make_float4(acc[c4*4], acc[c4*4+1], acc[c4*4+2], acc[c4*4+3]);
  }
  __syncthreads();

  // layer 3 (K=64) in two 32-col halves + maxpool + store
#pragma unroll
  for (int i = 0; i < 16; ++i) {
    const float4 v = *(const float4*)&A[row][4 * i];
    x[4*i+0] = v.x; x[4*i+1] = v.y; x[4*i+2] = v.z; x[4*i+3] = v.w;
  }
  const int c03 = (wid >> 1) << 6;
  const int g   = g0 + ((wid & 1) << 1) + (lane >> 5);
  float* og = out + (size_t)g * OUTn + c03;

#pragma unroll
  for (int h = 0; h < 2; ++h) {
    const int cb = c03 + h * 32;
#pragma unroll
    for (int c4 = 0; c4 < 8; ++c4) {
      const int cA = cb + c4 * 4;
      const float* w0 = Wout + (size_t)(cA + 0) * 64;
      const float* w1 = Wout + (size_t)(cA + 1) * 64;
      const float* w2 = Wout + (size_t)(cA + 2) * 64;
      const float* w3 = Wout + (size_t)(cA + 3) * 64;
      float s0 = bout[cA + 0], s1 = bout[cA + 1], s2 = bout[cA + 2], s3 = bout[cA + 3];
#pragma unroll
      for (int kq = 0; kq < 64; ++kq) {
        const float xv = x[kq];
        s0 = fmaf(xv, w0[kq], s0);
        s1 = fmaf(xv, w1[kq], s1);
        s2 = fmaf(xv, w2[kq], s2);
        s3 = fmaf(xv, w3[kq], s3);
      }
      acc[c4*4+0] = s0; acc[c4*4+1] = s1; acc[c4*4+2] = s2; acc[c4*4+3] = s3;
    }
#pragma unroll
    for (int cc = 0; cc < 32; ++cc) {
      float v = acc[cc];
      v = fmaxf(v, __shfl_xor(v, 1));
      v = fmaxf(v, __shfl_xor(v, 2));
      v = fmaxf(v, __shfl_xor(v, 4));
      v = fmaxf(v, __shfl_xor(v, 8));
      v = fmaxf(v, __shfl_xor(v, 16));
      acc[cc] = v;
    }
#pragma unroll
    for (int cc = 0; cc < 32; ++cc)
      if ((lane & 31) == cc) og[h * 32 + cc] = acc[cc];
  }
}

// ---------------------------------------------------------------------------
extern "C" void kernel_launch(void* const* d_in, const int* in_sizes, int n_in,
                              void* d_out, int out_size, void* d_ws, size_t ws_size,
                              hipStream_t stream)
{
  const float* xyz  = (const float*)d_in[0];
  const float* feat = (const float*)d_in[1];
  const float* W1   = (const float*)d_in[2];
  const float* b1   = (const float*)d_in[3];
  const float* g1   = (const float*)d_in[4];
  const float* be1  = (const float*)d_in[5];
  const float* W2   = (const float*)d_in[6];
  const float* b2   = (const float*)d_in[7];
  const float* g2   = (const float*)d_in[8];
  const float* be2  = (const float*)d_in[9];
  const float* Wout = (const float*)d_in[10];
  const float* bout = (const float*)d_in[11];

  float* outp = (float*)d_out;
  float* cent = outp;                             // (B, M, 3)
  float* o    = outp + (size_t)Bn * Mn * 3;       // (B, M, 128)

  fps_kernel<<<Bn, 256, 0, stream>>>(xyz, cent);
  sa2_kernel<<<Bn * Mn / 4, 256, 0, stream>>>(xyz, feat,
                                              W1, b1, g1, be1,
                                              W2, b2, g2, be2,
                                              Wout, bout, cent, o);
}

// Round 13
// 1278.473 us; speedup vs baseline: 2.0688x; 1.0571x over previous
//
#include <hip/hip_runtime.h>
#include <math.h>

#define Bn   16
#define Nn   4096
#define Cn   64
#define Mn   1024
#define Kn   32
#define OUTn 128
#define EPS  1e-5f

typedef unsigned long long u64;
typedef unsigned int u32;

__device__ __forceinline__ u64 u64min(u64 a, u64 b) { return a < b ? a : b; }
__device__ __forceinline__ u64 u64max(u64 a, u64 b) { return a > b ? a : b; }

template<int CTRL>
__device__ __forceinline__ u64 dpp_u64(u64 x) {
  union { u64 q; u32 w[2]; } in, out;
  in.q = x;
  out.w[0] = (u32)__builtin_amdgcn_update_dpp((int)in.w[0], (int)in.w[0], CTRL, 0xf, 0xf, false);
  out.w[1] = (u32)__builtin_amdgcn_update_dpp((int)in.w[1], (int)in.w[1], CTRL, 0xf, 0xf, false);
  return out.q;
}

// Canonical GCN wave64 reduce: row_shr 1,2,4,8 -> bcast15 -> bcast31.
// Result valid in lane 63. Pure VALU.
__device__ __forceinline__ u64 wave_max_dpp(u64 v) {
  v = u64max(v, dpp_u64<0x111>(v));
  v = u64max(v, dpp_u64<0x112>(v));
  v = u64max(v, dpp_u64<0x114>(v));
  v = u64max(v, dpp_u64<0x118>(v));
  v = u64max(v, dpp_u64<0x142>(v));
  v = u64max(v, dpp_u64<0x143>(v));
  return v;
}
__device__ __forceinline__ u64 wave_min_dpp(u64 v) {
  v = u64min(v, dpp_u64<0x111>(v));
  v = u64min(v, dpp_u64<0x112>(v));
  v = u64min(v, dpp_u64<0x114>(v));
  v = u64min(v, dpp_u64<0x118>(v));
  v = u64min(v, dpp_u64<0x142>(v));
  v = u64min(v, dpp_u64<0x143>(v));
  return v;
}

// ---------------------------------------------------------------------------
// FPS: r6 structure (best measured). One block/batch, 256 threads, 16
// pts/thread in regs. Keys (bits(d)<<32)|~n; u64 MAX == (max d, tie ->
// lowest n) == jnp.argmax first-max semantics. Per step: pack + depth-4 tree
// + DPP wave reduce (lane63) -> 4-partial LDS combine (parity buffers, ONE
// barrier) -> b128 centroid read.
// ---------------------------------------------------------------------------
__global__ __launch_bounds__(256) void fps_kernel(
    const float* __restrict__ xyz, float* __restrict__ cent)
{
  __shared__ float4 pts4[Nn];          // 64 KB
  __shared__ __align__(16) u64 pvq[2][4];

  const int b = blockIdx.x;
  const int t = threadIdx.x;
  const float* src = xyz + (size_t)b * Nn * 3;

  for (int i = t; i < Nn; i += 256) {
    pts4[i] = make_float4(src[3*i+0], src[3*i+1], src[3*i+2], 0.0f);
  }
  __syncthreads();

  const float4 c0 = pts4[0];

  float px[16], py[16], pz[16], d[16];
  u32 ninv[16];
#pragma unroll
  for (int j = 0; j < 16; ++j) {
    const int n = j * 256 + t;
    ninv[j] = (u32)(~n);
    const float4 p = pts4[n];
    px[j] = p.x; py[j] = p.y; pz[j] = p.z;
    const float dx = px[j] - c0.x, dy = py[j] - c0.y, dz = pz[j] - c0.z;
    d[j] = (dx * dx + dy * dy) + dz * dz;
  }

  if (t == 0) {
    float* o = cent + (size_t)b * Mn * 3;
    o[0] = c0.x; o[1] = c0.y; o[2] = c0.z;
  }

  for (int m = 1; m < Mn; ++m) {
    u64 k[16];
#pragma unroll
    for (int j = 0; j < 16; ++j)
      k[j] = ((u64)__float_as_uint(d[j]) << 32) | ninv[j];
#pragma unroll
    for (int st = 1; st < 16; st <<= 1)
#pragma unroll
      for (int j = 0; j < 16; j += (st << 1))
        k[j] = u64max(k[j], k[j + st]);

    const u64 bk = wave_max_dpp(k[0]);
    const int par = m & 1;
    if ((t & 63) == 63) pvq[par][t >> 6] = bk;
    __syncthreads();

    const u64 f = u64max(u64max(pvq[par][0], pvq[par][1]),
                         u64max(pvq[par][2], pvq[par][3]));
    const int fi = (int)(~(u32)f);      // low word was ~n

    const float4 cp = pts4[fi];
    if (t == 0) {
      float* o = cent + ((size_t)b * Mn + m) * 3;
      o[0] = cp.x; o[1] = cp.y; o[2] = cp.z;
    }

#pragma unroll
    for (int j = 0; j < 16; ++j) {
      const float dx = px[j] - cp.x, dy = py[j] - cp.y, dz = pz[j] - cp.z;
      const float nd = (dx * dx + dy * dy) + dz * dz;
      d[j] = fminf(d[j], nd);
    }
  }
}

// ---------------------------------------------------------------------------
// KNN: ONE WAVE per centroid (4 centroids/block), ZERO LDS, zero barriers ->
// high occupancy for the latency-bound extraction chain (the r12 fusion lost
// ~130us by dragging the MLP's 37KB LDS through this phase).
// Keys (mono(bits(d2))<<32)|n; u64 MIN == (min d2, tie -> lowest idx) ==
// stable top_k set. Writes sel into the o-region of d_out (punned int),
// which mlp_kernel reads before overwriting.
// ---------------------------------------------------------------------------
__global__ __launch_bounds__(256) void knn_kernel(
    const float* __restrict__ xyz, const float* __restrict__ cent,
    int* __restrict__ osel)
{
  const int t    = threadIdx.x;
  const int lane = t & 63;
  const int wid  = __builtin_amdgcn_readfirstlane(t >> 6);
  const int g    = (blockIdx.x << 2) + wid;      // centroid id
  const int b    = g >> 10;
  const float* P = xyz + (size_t)b * Nn * 3;

  const float cx = cent[(size_t)g * 3 + 0];
  const float cy = cent[(size_t)g * 3 + 1];
  const float cz = cent[(size_t)g * 3 + 2];
  const float cc2 = (cx * cx + cy * cy) + cz * cz;

  u64 kk[4][16];
  u64 gm0, gm1, gm2, gm3;

#pragma unroll
  for (int grp = 0; grp < 4; ++grp) {
#pragma unroll
    for (int j = 0; j < 16; ++j) {
      const int n = grp * 1024 + j * 64 + lane;
      const float x = P[n*3+0], y = P[n*3+1], z = P[n*3+2];
      const float pp = (x * x + y * y) + z * z;
      const float dt = (cx * x + cy * y) + cz * z;
      const float d2 = (cc2 + pp) - 2.0f * dt;
      const u32 bu = __float_as_uint(d2);
      const u32 mo = bu ^ (0x80000000u | (u32)((int)bu >> 31)); // order-preserving
      kk[grp][j] = ((u64)mo << 32) | (u32)n;
    }
  }
#define TREE16(dst, A_)                                                 \
  {                                                                     \
    u64 t0 = u64min(A_[0], A_[1]),  t1 = u64min(A_[2], A_[3]);          \
    u64 t2 = u64min(A_[4], A_[5]),  t3 = u64min(A_[6], A_[7]);          \
    u64 t4 = u64min(A_[8], A_[9]),  t5 = u64min(A_[10], A_[11]);        \
    u64 t6 = u64min(A_[12], A_[13]), t7 = u64min(A_[14], A_[15]);       \
    t0 = u64min(t0, t1); t2 = u64min(t2, t3);                           \
    t4 = u64min(t4, t5); t6 = u64min(t6, t7);                           \
    dst = u64min(u64min(t0, t2), u64min(t4, t6));                       \
  }
  TREE16(gm0, kk[0]); TREE16(gm1, kk[1]);
  TREE16(gm2, kk[2]); TREE16(gm3, kk[3]);
  u64 bk = u64min(u64min(gm0, gm1), u64min(gm2, gm3));

  int myfi = 0;
  for (int s = 0; s < Kn; ++s) {
    const u64 v = wave_min_dpp(bk);
    const u32 flo = (u32)__builtin_amdgcn_readlane((int)(u32)v, 63);
    const int fi = (int)flo;                       // point index (uniform)
    if (lane == s) myfi = fi;

    const int og = __builtin_amdgcn_readfirstlane(fi >> 10);       // group
    const int oj = __builtin_amdgcn_readfirstlane((fi >> 6) & 15); // slot
    if (lane == (fi & 63)) {                       // unique owner lane
#pragma unroll
      for (int grp = 0; grp < 4; ++grp) {
        if (grp == og) {
#pragma unroll
          for (int j = 0; j < 16; ++j)
            if (j == oj) kk[grp][j] = ~0ull;
          u64 nm;
          TREE16(nm, kk[grp]);
          if (grp == 0) gm0 = nm;
          else if (grp == 1) gm1 = nm;
          else if (grp == 2) gm2 = nm;
          else gm3 = nm;
        }
      }
      bk = u64min(u64min(gm0, gm1), u64min(gm2, gm3));
    }
  }
#undef TREE16

  if (lane < Kn) osel[(size_t)g * 128 + lane] = myfi;
}

// ---------------------------------------------------------------------------
// MLP: one block (256 thr) per 4 centroids = 128 rows (r8 version).
// Row hoisted to 64 VGPRs per layer; cc-outer jammed x4 (four independent
// 64-deep FMA chains over contiguous, wave-uniform weight rows). Layer 3 in
// two 32-col halves. LN via cross-wave LDS partial exchange.
// ---------------------------------------------------------------------------
__global__ __launch_bounds__(256) void mlp_kernel(
    const float* __restrict__ xyz, const float* __restrict__ feat,
    const float* __restrict__ W1, const float* __restrict__ b1,
    const float* __restrict__ g1, const float* __restrict__ be1,
    const float* __restrict__ W2, const float* __restrict__ b2,
    const float* __restrict__ g2, const float* __restrict__ be2,
    const float* __restrict__ Wout, const float* __restrict__ bout,
    const float* __restrict__ cent, float* __restrict__ out)
{
  __shared__ float A[128][68];
  __shared__ float lnS[2][128];
  __shared__ float lnQ[2][128];

  const int bm0 = blockIdx.x << 2;
  const int b   = bm0 >> 10;
  const int t   = threadIdx.x;
  const int wid = __builtin_amdgcn_readfirstlane(t >> 6);
  const int lane = t & 63;

  const float* F = feat + (size_t)b * Nn * Cn;
  const float* P = xyz  + (size_t)b * Nn * 3;
  const int* osel = (const int*)out;

  // ---- gather: 2 threads per row ----
  {
    const int row = t >> 1, half = t & 1;
    const int g = bm0 + (row >> 5);
    const int n = osel[(size_t)g * 128 + (row & 31)];
    const float4* f4 = (const float4*)(F + (size_t)n * Cn + half * 32);
#pragma unroll
    for (int q = 0; q < 8; ++q)
      *(float4*)&A[row][half * 32 + q * 4] = f4[q];
    if (half) {
      A[row][64] = P[n*3+0] - cent[(size_t)g*3+0];
      A[row][65] = P[n*3+1] - cent[(size_t)g*3+1];
      A[row][66] = P[n*3+2] - cent[(size_t)g*3+2];
      A[row][67] = 0.0f;
    }
  }
  __syncthreads();

  const int row  = ((wid & 1) << 6) + lane;
  const int c0   = (wid >> 1) << 5;
  const int slot = wid >> 1;

  float x[64];
  float acc[32];

#pragma unroll
  for (int i = 0; i < 16; ++i) {
    const float4 v = *(const float4*)&A[row][4 * i];
    x[4*i+0] = v.x; x[4*i+1] = v.y; x[4*i+2] = v.z; x[4*i+3] = v.w;
  }
  const float xc0 = A[row][64], xc1 = A[row][65], xc2 = A[row][66];

  // ---- layer 1 (K=67): X cols 0..63 -> W1 cols 3..66; coords -> W1 0..2 ----
#pragma unroll
  for (int c4 = 0; c4 < 8; ++c4) {
    const int cA = c0 + c4 * 4;
    const float* w0 = W1 + (size_t)(cA + 0) * 67;
    const float* w1 = W1 + (size_t)(cA + 1) * 67;
    const float* w2 = W1 + (size_t)(cA + 2) * 67;
    const float* w3 = W1 + (size_t)(cA + 3) * 67;
    float s0 = fmaf(xc2, w0[2], fmaf(xc1, w0[1], fmaf(xc0, w0[0], b1[cA + 0])));
    float s1 = fmaf(xc2, w1[2], fmaf(xc1, w1[1], fmaf(xc0, w1[0], b1[cA + 1])));
    float s2 = fmaf(xc2, w2[2], fmaf(xc1, w2[1], fmaf(xc0, w2[0], b1[cA + 2])));
    float s3 = fmaf(xc2, w3[2], fmaf(xc1, w3[1], fmaf(xc0, w3[0], b1[cA + 3])));
#pragma unroll
    for (int kq = 0; kq < 64; ++kq) {
      const float xv = x[kq];
      s0 = fmaf(xv, w0[3 + kq], s0);
      s1 = fmaf(xv, w1[3 + kq], s1);
      s2 = fmaf(xv, w2[3 + kq], s2);
      s3 = fmaf(xv, w3[3 + kq], s3);
    }
    acc[c4*4+0] = s0; acc[c4*4+1] = s1; acc[c4*4+2] = s2; acc[c4*4+3] = s3;
  }

  // ---- LN1 + ReLU -> A ----
  {
    float s = 0.0f, q = 0.0f;
#pragma unroll
    for (int cc = 0; cc < 32; ++cc) { s += acc[cc]; q = fmaf(acc[cc], acc[cc], q); }
    lnS[slot][row] = s; lnQ[slot][row] = q;
    __syncthreads();
    const float st = s + lnS[slot ^ 1][row];
    const float qt = q + lnQ[slot ^ 1][row];
    const float mu = st * 0.015625f;
    const float var = qt * 0.015625f - mu * mu;
    const float rs = rsqrtf(var + EPS);
#pragma unroll
    for (int cc = 0; cc < 32; ++cc) {
      const float y = (acc[cc] - mu) * rs * g1[c0 + cc] + be1[c0 + cc];
      acc[cc] = fmaxf(y, 0.0f);
    }
#pragma unroll
    for (int c4 = 0; c4 < 8; ++c4)
      *(float4*)&A[row][c0 + c4 * 4] =
          make_float4(acc[c4*4], acc[c4*4+1], acc[c4*4+2], acc[c4*4+3]);
  }
  __syncthreads();

  // ---- layer 2 (K=64) ----
#pragma unroll
  for (int i = 0; i < 16; ++i) {
    const float4 v = *(const float4*)&A[row][4 * i];
    x[4*i+0] = v.x; x[4*i+1] = v.y; x[4*i+2] = v.z; x[4*i+3] = v.w;
  }
#pragma unroll
  for (int c4 = 0; c4 < 8; ++c4) {
    const int cA = c0 + c4 * 4;
    const float* w0 = W2 + (size_t)(cA + 0) * 64;
    const float* w1 = W2 + (size_t)(cA + 1) * 64;
    const float* w2 = W2 + (size_t)(cA + 2) * 64;
    const float* w3 = W2 + (size_t)(cA + 3) * 64;
    float s0 = b2[cA + 0], s1 = b2[cA + 1], s2 = b2[cA + 2], s3 = b2[cA + 3];
#pragma unroll
    for (int kq = 0; kq < 64; ++kq) {
      const float xv = x[kq];
      s0 = fmaf(xv, w0[kq], s0);
      s1 = fmaf(xv, w1[kq], s1);
      s2 = fmaf(xv, w2[kq], s2);
      s3 = fmaf(xv, w3[kq], s3);
    }
    acc[c4*4+0] = s0; acc[c4*4+1] = s1; acc[c4*4+2] = s2; acc[c4*4+3] = s3;
  }

  // ---- LN2 + ReLU -> A ----
  {
    float s = 0.0f, q = 0.0f;
#pragma unroll
    for (int cc = 0; cc < 32; ++cc) { s += acc[cc]; q = fmaf(acc[cc], acc[cc], q); }
    lnS[slot][row] = s; lnQ[slot][row] = q;
    __syncthreads();
    const float st = s + lnS[slot ^ 1][row];
    const float qt = q + lnQ[slot ^ 1][row];
    const float mu = st * 0.015625f;
    const float var = qt * 0.015625f - mu * mu;
    const float rs = rsqrtf(var + EPS);
#pragma unroll
    for (int cc = 0; cc < 32; ++cc) {
      const float y = (acc[cc] - mu) * rs * g2[c0 + cc] + be2[c0 + cc];
      acc[cc] = fmaxf(y, 0.0f);
    }
#pragma unroll
    for (int c4 = 0; c4 < 8; ++c4)
      *(float4*)&A[row][c0 + c4 * 4] =
          make_float4(acc[c4*4], acc[c4*4+1], acc[c4*4+2], acc[c4*4+3]);
  }
  __syncthreads();

  // ---- layer 3 (K=64) in two 32-col halves + maxpool + store ----
#pragma unroll
  for (int i = 0; i < 16; ++i) {
    const float4 v = *(const float4*)&A[row][4 * i];
    x[4*i+0] = v.x; x[4*i+1] = v.y; x[4*i+2] = v.z; x[4*i+3] = v.w;
  }
  const int c03 = (wid >> 1) << 6;
  const int g   = bm0 + ((wid & 1) << 1) + (lane >> 5);
  float* og = out + (size_t)g * OUTn + c03;

#pragma unroll
  for (int h = 0; h < 2; ++h) {
    const int cb = c03 + h * 32;
#pragma unroll
    for (int c4 = 0; c4 < 8; ++c4) {
      const int cA = cb + c4 * 4;
      const float* w0 = Wout + (size_t)(cA + 0) * 64;
      const float* w1 = Wout + (size_t)(cA + 1) * 64;
      const float* w2 = Wout + (size_t)(cA + 2) * 64;
      const float* w3 = Wout + (size_t)(cA + 3) * 64;
      float s0 = bout[cA + 0], s1 = bout[cA + 1], s2 = bout[cA + 2], s3 = bout[cA + 3];
#pragma unroll
      for (int kq = 0; kq < 64; ++kq) {
        const float xv = x[kq];
        s0 = fmaf(xv, w0[kq], s0);
        s1 = fmaf(xv, w1[kq], s1);
        s2 = fmaf(xv, w2[kq], s2);
        s3 = fmaf(xv, w3[kq], s3);
      }
      acc[c4*4+0] = s0; acc[c4*4+1] = s1; acc[c4*4+2] = s2; acc[c4*4+3] = s3;
    }
#pragma unroll
    for (int cc = 0; cc < 32; ++cc) {
      float v = acc[cc];
      v = fmaxf(v, __shfl_xor(v, 1));
      v = fmaxf(v, __shfl_xor(v, 2));
      v = fmaxf(v, __shfl_xor(v, 4));
      v = fmaxf(v, __shfl_xor(v, 8));
      v = fmaxf(v, __shfl_xor(v, 16));
      acc[cc] = v;
    }
#pragma unroll
    for (int cc = 0; cc < 32; ++cc)
      if ((lane & 31) == cc) og[h * 32 + cc] = acc[cc];
  }
}

// ---------------------------------------------------------------------------
extern "C" void kernel_launch(void* const* d_in, const int* in_sizes, int n_in,
                              void* d_out, int out_size, void* d_ws, size_t ws_size,
                              hipStream_t stream)
{
  const float* xyz  = (const float*)d_in[0];
  const float* feat = (const float*)d_in[1];
  const float* W1   = (const float*)d_in[2];
  const float* b1   = (const float*)d_in[3];
  const float* g1   = (const float*)d_in[4];
  const float* be1  = (const float*)d_in[5];
  const float* W2   = (const float*)d_in[6];
  const float* b2   = (const float*)d_in[7];
  const float* g2   = (const float*)d_in[8];
  const float* be2  = (const float*)d_in[9];
  const float* Wout = (const float*)d_in[10];
  const float* bout = (const float*)d_in[11];

  float* outp = (float*)d_out;
  float* cent = outp;                             // (B, M, 3)
  float* o    = outp + (size_t)Bn * Mn * 3;       // (B, M, 128)

  fps_kernel<<<Bn, 256, 0, stream>>>(xyz, cent);
  knn_kernel<<<Bn * Mn / 4, 256, 0, stream>>>(xyz, cent, (int*)o);
  mlp_kernel<<<Bn * Mn / 4, 256, 0, stream>>>(xyz, feat,
                                              W1, b1, g1, be1,
                                              W2, b2, g2, be2,
                                              Wout, bout, cent, o);
}

// Round 14
// 1077.773 us; speedup vs baseline: 2.4541x; 1.1862x over previous
//
#include <hip/hip_runtime.h>
#include <math.h>

#define Bn   16
#define Nn   4096
#define Cn   64
#define Mn   1024
#define Kn   32
#define OUTn 128
#define EPS  1e-5f

typedef unsigned long long u64;
typedef unsigned int u32;
typedef __attribute__((ext_vector_type(8))) short bf16x8;
typedef __attribute__((ext_vector_type(4))) float f32x4;

__device__ __forceinline__ u64 u64min(u64 a, u64 b) { return a < b ? a : b; }
__device__ __forceinline__ u64 u64max(u64 a, u64 b) { return a > b ? a : b; }

template<int CTRL>
__device__ __forceinline__ u64 dpp_u64(u64 x) {
  union { u64 q; u32 w[2]; } in, out;
  in.q = x;
  out.w[0] = (u32)__builtin_amdgcn_update_dpp((int)in.w[0], (int)in.w[0], CTRL, 0xf, 0xf, false);
  out.w[1] = (u32)__builtin_amdgcn_update_dpp((int)in.w[1], (int)in.w[1], CTRL, 0xf, 0xf, false);
  return out.q;
}

__device__ __forceinline__ u64 wave_max_dpp(u64 v) {
  v = u64max(v, dpp_u64<0x111>(v));
  v = u64max(v, dpp_u64<0x112>(v));
  v = u64max(v, dpp_u64<0x114>(v));
  v = u64max(v, dpp_u64<0x118>(v));
  v = u64max(v, dpp_u64<0x142>(v));
  v = u64max(v, dpp_u64<0x143>(v));
  return v;
}
__device__ __forceinline__ u64 wave_min_dpp(u64 v) {
  v = u64min(v, dpp_u64<0x111>(v));
  v = u64min(v, dpp_u64<0x112>(v));
  v = u64min(v, dpp_u64<0x114>(v));
  v = u64min(v, dpp_u64<0x118>(v));
  v = u64min(v, dpp_u64<0x142>(v));
  v = u64min(v, dpp_u64<0x143>(v));
  return v;
}

// RTN f32->bf16 pack helpers
__device__ __forceinline__ u32 rnd2(float a, float b) {
  u32 ua = __float_as_uint(a);
  ua = (ua + 0x7FFFu + ((ua >> 16) & 1u)) >> 16;
  u32 ub = __float_as_uint(b);
  ub = (ub + 0x7FFFu + ((ub >> 16) & 1u)) & 0xFFFF0000u;
  return ua | ub;
}
__device__ __forceinline__ short bf16s(float a) {
  u32 ua = __float_as_uint(a);
  return (short)((ua + 0x7FFFu + ((ua >> 16) & 1u)) >> 16);
}
// 8 consecutive f32 -> bf16x8 fragment
__device__ __forceinline__ bf16x8 wfrag(const float* __restrict__ w8) {
  union { u32 u[4]; bf16x8 v; } r;
  r.u[0] = rnd2(w8[0], w8[1]); r.u[1] = rnd2(w8[2], w8[3]);
  r.u[2] = rnd2(w8[4], w8[5]); r.u[3] = rnd2(w8[6], w8[7]);
  return r.v;
}

// ---------------------------------------------------------------------------
// FPS: r13 version, byte-identical (best measured: 647 us).
// ---------------------------------------------------------------------------
__global__ __launch_bounds__(256) void fps_kernel(
    const float* __restrict__ xyz, float* __restrict__ cent)
{
  __shared__ float4 pts4[Nn];          // 64 KB
  __shared__ __align__(16) u64 pvq[2][4];

  const int b = blockIdx.x;
  const int t = threadIdx.x;
  const float* src = xyz + (size_t)b * Nn * 3;

  for (int i = t; i < Nn; i += 256) {
    pts4[i] = make_float4(src[3*i+0], src[3*i+1], src[3*i+2], 0.0f);
  }
  __syncthreads();

  const float4 c0 = pts4[0];

  float px[16], py[16], pz[16], d[16];
  u32 ninv[16];
#pragma unroll
  for (int j = 0; j < 16; ++j) {
    const int n = j * 256 + t;
    ninv[j] = (u32)(~n);
    const float4 p = pts4[n];
    px[j] = p.x; py[j] = p.y; pz[j] = p.z;
    const float dx = px[j] - c0.x, dy = py[j] - c0.y, dz = pz[j] - c0.z;
    d[j] = (dx * dx + dy * dy) + dz * dz;
  }

  if (t == 0) {
    float* o = cent + (size_t)b * Mn * 3;
    o[0] = c0.x; o[1] = c0.y; o[2] = c0.z;
  }

  for (int m = 1; m < Mn; ++m) {
    u64 k[16];
#pragma unroll
    for (int j = 0; j < 16; ++j)
      k[j] = ((u64)__float_as_uint(d[j]) << 32) | ninv[j];
#pragma unroll
    for (int st = 1; st < 16; st <<= 1)
#pragma unroll
      for (int j = 0; j < 16; j += (st << 1))
        k[j] = u64max(k[j], k[j + st]);

    const u64 bk = wave_max_dpp(k[0]);
    const int par = m & 1;
    if ((t & 63) == 63) pvq[par][t >> 6] = bk;
    __syncthreads();

    const u64 f = u64max(u64max(pvq[par][0], pvq[par][1]),
                         u64max(pvq[par][2], pvq[par][3]));
    const int fi = (int)(~(u32)f);

    const float4 cp = pts4[fi];
    if (t == 0) {
      float* o = cent + ((size_t)b * Mn + m) * 3;
      o[0] = cp.x; o[1] = cp.y; o[2] = cp.z;
    }

#pragma unroll
    for (int j = 0; j < 16; ++j) {
      const float dx = px[j] - cp.x, dy = py[j] - cp.y, dz = pz[j] - cp.z;
      const float nd = (dx * dx + dy * dy) + dz * dz;
      d[j] = fminf(d[j], nd);
    }
  }
}

// ---------------------------------------------------------------------------
// KNN: r13 version, byte-identical (one wave/centroid, zero LDS/barriers).
// ---------------------------------------------------------------------------
__global__ __launch_bounds__(256) void knn_kernel(
    const float* __restrict__ xyz, const float* __restrict__ cent,
    int* __restrict__ osel)
{
  const int t    = threadIdx.x;
  const int lane = t & 63;
  const int wid  = __builtin_amdgcn_readfirstlane(t >> 6);
  const int g    = (blockIdx.x << 2) + wid;
  const int b    = g >> 10;
  const float* P = xyz + (size_t)b * Nn * 3;

  const float cx = cent[(size_t)g * 3 + 0];
  const float cy = cent[(size_t)g * 3 + 1];
  const float cz = cent[(size_t)g * 3 + 2];
  const float cc2 = (cx * cx + cy * cy) + cz * cz;

  u64 kk[4][16];
  u64 gm0, gm1, gm2, gm3;

#pragma unroll
  for (int grp = 0; grp < 4; ++grp) {
#pragma unroll
    for (int j = 0; j < 16; ++j) {
      const int n = grp * 1024 + j * 64 + lane;
      const float x = P[n*3+0], y = P[n*3+1], z = P[n*3+2];
      const float pp = (x * x + y * y) + z * z;
      const float dt = (cx * x + cy * y) + cz * z;
      const float d2 = (cc2 + pp) - 2.0f * dt;
      const u32 bu = __float_as_uint(d2);
      const u32 mo = bu ^ (0x80000000u | (u32)((int)bu >> 31));
      kk[grp][j] = ((u64)mo << 32) | (u32)n;
    }
  }
#define TREE16(dst, A_)                                                 \
  {                                                                     \
    u64 t0 = u64min(A_[0], A_[1]),  t1 = u64min(A_[2], A_[3]);          \
    u64 t2 = u64min(A_[4], A_[5]),  t3 = u64min(A_[6], A_[7]);          \
    u64 t4 = u64min(A_[8], A_[9]),  t5 = u64min(A_[10], A_[11]);        \
    u64 t6 = u64min(A_[12], A_[13]), t7 = u64min(A_[14], A_[15]);       \
    t0 = u64min(t0, t1); t2 = u64min(t2, t3);                           \
    t4 = u64min(t4, t5); t6 = u64min(t6, t7);                           \
    dst = u64min(u64min(t0, t2), u64min(t4, t6));                       \
  }
  TREE16(gm0, kk[0]); TREE16(gm1, kk[1]);
  TREE16(gm2, kk[2]); TREE16(gm3, kk[3]);
  u64 bk = u64min(u64min(gm0, gm1), u64min(gm2, gm3));

  int myfi = 0;
  for (int s = 0; s < Kn; ++s) {
    const u64 v = wave_min_dpp(bk);
    const u32 flo = (u32)__builtin_amdgcn_readlane((int)(u32)v, 63);
    const int fi = (int)flo;
    if (lane == s) myfi = fi;

    const int og = __builtin_amdgcn_readfirstlane(fi >> 10);
    const int oj = __builtin_amdgcn_readfirstlane((fi >> 6) & 15);
    if (lane == (fi & 63)) {
#pragma unroll
      for (int grp = 0; grp < 4; ++grp) {
        if (grp == og) {
#pragma unroll
          for (int j = 0; j < 16; ++j)
            if (j == oj) kk[grp][j] = ~0ull;
          u64 nm;
          TREE16(nm, kk[grp]);
          if (grp == 0) gm0 = nm;
          else if (grp == 1) gm1 = nm;
          else if (grp == 2) gm2 = nm;
          else gm3 = nm;
        }
      }
      bk = u64min(u64min(gm0, gm1), u64min(gm2, gm3));
    }
  }
#undef TREE16

  if (lane < Kn) osel[(size_t)g * 128 + lane] = myfi;
}

// ---------------------------------------------------------------------------
// MLP via bf16 MFMA (v_mfma_f32_16x16x32_bf16). One block per 4 centroids;
// wave w owns centroid w's 32 rows x all 64 cols -> LN and maxpool fully
// in-wave; ONE barrier total (post-gather). X staged bf16 in LDS [128][104]
// (stride 52 dwords: frag reads 2-way bank = free). K-order: feats 0..63,
// coords 64..66, zeros 67..95 -> W1 frag k-mapping kx<64 -> W1[.,3+kx],
// tail frag = masked coord weights. W frags packed RTN from global f32.
// Fragment layouts (AMD calc / guide m89): A row=l&15, k=8*(l>>4)+e;
// B col=l&15, same k; C/D col=l&15, row=4*(l>>4)+reg.
// ---------------------------------------------------------------------------
__global__ __launch_bounds__(256) void mlp_kernel(
    const float* __restrict__ xyz, const float* __restrict__ feat,
    const float* __restrict__ W1, const float* __restrict__ b1,
    const float* __restrict__ g1, const float* __restrict__ be1,
    const float* __restrict__ W2, const float* __restrict__ b2,
    const float* __restrict__ g2, const float* __restrict__ be2,
    const float* __restrict__ Wout, const float* __restrict__ bout,
    const float* __restrict__ cent, float* __restrict__ out)
{
  __shared__ u32 Xw[128][52];        // 128 rows x 104 bf16 (26.6 KB)

  const int g0   = blockIdx.x << 2;
  const int b    = g0 >> 10;
  const int t    = threadIdx.x;
  const int wid  = __builtin_amdgcn_readfirstlane(t >> 6);
  const int lane = t & 63;

  const float* P = xyz  + (size_t)b * Nn * 3;
  const float* F = feat + (size_t)b * Nn * Cn;
  const int* osel = (const int*)out;

  // ---- gather -> bf16 LDS (2 threads per row) ----
  {
    const int row = t >> 1, half = t & 1;
    const int gi = g0 + (row >> 5);
    const int n = osel[(size_t)gi * 128 + (row & 31)];
    const float* fr = F + (size_t)n * Cn + 32 * half;
#pragma unroll
    for (int q = 0; q < 4; ++q) {
      const float4 a = ((const float4*)fr)[2*q];
      const float4 c = ((const float4*)fr)[2*q+1];
      uint4 wv;
      wv.x = rnd2(a.x, a.y); wv.y = rnd2(a.z, a.w);
      wv.z = rnd2(c.x, c.y); wv.w = rnd2(c.z, c.w);
      *(uint4*)&Xw[row][16*half + 4*q] = wv;
    }
    if (half) {
      const float pxc = P[n*3+0] - cent[(size_t)gi*3+0];
      const float pyc = P[n*3+1] - cent[(size_t)gi*3+1];
      const float pzc = P[n*3+2] - cent[(size_t)gi*3+2];
      Xw[row][32] = rnd2(pxc, pyc);
      Xw[row][33] = rnd2(pzc, 0.0f);
      Xw[row][34] = 0; Xw[row][35] = 0;
#pragma unroll
      for (int q2 = 0; q2 < 4; ++q2) {
        uint4 z; z.x = z.y = z.z = z.w = 0;
        *(uint4*)&Xw[row][36 + 4*q2] = z;
      }
    }
  }
  __syncthreads();

  const int c  = lane & 15;          // frag col / A-row low
  const int gq = lane >> 4;          // frag k-group / C-row group
  const int R0 = wid << 5;           // wave's first row (centroid wid)
  const short* xs_base = (const short*)Xw;

  f32x4 acc[2][4];

  // ================= layer 1: K=96 (feats 64 | coords 3 | zero pad) ======
#pragma unroll
  for (int nt = 0; nt < 4; ++nt) {
    const float bv = b1[16*nt + c];
    acc[0][nt] = (f32x4){bv, bv, bv, bv};
    acc[1][nt] = (f32x4){bv, bv, bv, bv};
  }
#pragma unroll
  for (int ks = 0; ks < 3; ++ks) {
    const bf16x8 af0 = *(const bf16x8*)(xs_base + (R0 +      c) * 104 + 32*ks + 8*gq);
    const bf16x8 af1 = *(const bf16x8*)(xs_base + (R0 + 16 + c) * 104 + 32*ks + 8*gq);
#pragma unroll
    for (int nt = 0; nt < 4; ++nt) {
      const int n = 16*nt + c;
      bf16x8 bf;
      if (ks < 2) {
        bf = wfrag(W1 + (size_t)n * 67 + 3 + 32*ks + 8*gq);
      } else {
        union { u32 u[4]; bf16x8 v; } r;
        r.u[0] = r.u[1] = r.u[2] = r.u[3] = 0;
        if (gq == 0) {
          const float* w = W1 + (size_t)n * 67;
          r.u[0] = rnd2(w[0], w[1]);
          r.u[1] = rnd2(w[2], 0.0f);
        }
        bf = r.v;
      }
      acc[0][nt] = __builtin_amdgcn_mfma_f32_16x16x32_bf16(af0, bf, acc[0][nt], 0, 0, 0);
      acc[1][nt] = __builtin_amdgcn_mfma_f32_16x16x32_bf16(af1, bf, acc[1][nt], 0, 0, 0);
    }
  }

  // ---- LN1 + ReLU (in-wave) -> Xw bf16 cols 0..63 ----
  {
    float gg[4], bb[4];
#pragma unroll
    for (int nt = 0; nt < 4; ++nt) { gg[nt] = g1[16*nt + c]; bb[nt] = be1[16*nt + c]; }
#pragma unroll
    for (int mt = 0; mt < 2; ++mt) {
#pragma unroll
      for (int r = 0; r < 4; ++r) {
        const float v0 = acc[mt][0][r], v1 = acc[mt][1][r];
        const float v2 = acc[mt][2][r], v3 = acc[mt][3][r];
        float s = (v0 + v1) + (v2 + v3);
        float q = fmaf(v0, v0, fmaf(v1, v1, fmaf(v2, v2, v3 * v3)));
#pragma unroll
        for (int off = 1; off < 16; off <<= 1) {
          s += __shfl_xor(s, off);
          q += __shfl_xor(q, off);
        }
        const float mu = s * 0.015625f;
        const float var = q * 0.015625f - mu * mu;
        const float rs = rsqrtf(var + EPS);
        const int row = R0 + 16*mt + 4*gq + r;
        short* xsw = (short*)Xw + row * 104;
#pragma unroll
        for (int nt = 0; nt < 4; ++nt) {
          const float y = fmaxf((acc[mt][nt][r] - mu) * rs * gg[nt] + bb[nt], 0.0f);
          xsw[16*nt + c] = bf16s(y);
        }
      }
    }
  }

  // ================= layer 2: K=64 =================
#pragma unroll
  for (int nt = 0; nt < 4; ++nt) {
    const float bv = b2[16*nt + c];
    acc[0][nt] = (f32x4){bv, bv, bv, bv};
    acc[1][nt] = (f32x4){bv, bv, bv, bv};
  }
#pragma unroll
  for (int ks = 0; ks < 2; ++ks) {
    const bf16x8 af0 = *(const bf16x8*)(xs_base + (R0 +      c) * 104 + 32*ks + 8*gq);
    const bf16x8 af1 = *(const bf16x8*)(xs_base + (R0 + 16 + c) * 104 + 32*ks + 8*gq);
#pragma unroll
    for (int nt = 0; nt < 4; ++nt) {
      const bf16x8 bf = wfrag(W2 + (size_t)(16*nt + c) * 64 + 32*ks + 8*gq);
      acc[0][nt] = __builtin_amdgcn_mfma_f32_16x16x32_bf16(af0, bf, acc[0][nt], 0, 0, 0);
      acc[1][nt] = __builtin_amdgcn_mfma_f32_16x16x32_bf16(af1, bf, acc[1][nt], 0, 0, 0);
    }
  }

  // ---- LN2 + ReLU (in-wave) -> Xw bf16 cols 0..63 ----
  {
    float gg[4], bb[4];
#pragma unroll
    for (int nt = 0; nt < 4; ++nt) { gg[nt] = g2[16*nt + c]; bb[nt] = be2[16*nt + c]; }
#pragma unroll
    for (int mt = 0; mt < 2; ++mt) {
#pragma unroll
      for (int r = 0; r < 4; ++r) {
        const float v0 = acc[mt][0][r], v1 = acc[mt][1][r];
        const float v2 = acc[mt][2][r], v3 = acc[mt][3][r];
        float s = (v0 + v1) + (v2 + v3);
        float q = fmaf(v0, v0, fmaf(v1, v1, fmaf(v2, v2, v3 * v3)));
#pragma unroll
        for (int off = 1; off < 16; off <<= 1) {
          s += __shfl_xor(s, off);
          q += __shfl_xor(q, off);
        }
        const float mu = s * 0.015625f;
        const float var = q * 0.015625f - mu * mu;
        const float rs = rsqrtf(var + EPS);
        const int row = R0 + 16*mt + 4*gq + r;
        short* xsw = (short*)Xw + row * 104;
#pragma unroll
        for (int nt = 0; nt < 4; ++nt) {
          const float y = fmaxf((acc[mt][nt][r] - mu) * rs * gg[nt] + bb[nt], 0.0f);
          xsw[16*nt + c] = bf16s(y);
        }
      }
    }
  }

  // ================= layer 3: N=128 in two 64-col halves + maxpool =======
  float* og = out + (size_t)(g0 + wid) * OUTn;
#pragma unroll
  for (int h = 0; h < 2; ++h) {
#pragma unroll
    for (int nt = 0; nt < 4; ++nt) {
      const float bv = bout[64*h + 16*nt + c];
      acc[0][nt] = (f32x4){bv, bv, bv, bv};
      acc[1][nt] = (f32x4){bv, bv, bv, bv};
    }
#pragma unroll
    for (int ks = 0; ks < 2; ++ks) {
      const bf16x8 af0 = *(const bf16x8*)(xs_base + (R0 +      c) * 104 + 32*ks + 8*gq);
      const bf16x8 af1 = *(const bf16x8*)(xs_base + (R0 + 16 + c) * 104 + 32*ks + 8*gq);
#pragma unroll
      for (int nt = 0; nt < 4; ++nt) {
        const bf16x8 bf = wfrag(Wout + (size_t)(64*h + 16*nt + c) * 64 + 32*ks + 8*gq);
        acc[0][nt] = __builtin_amdgcn_mfma_f32_16x16x32_bf16(af0, bf, acc[0][nt], 0, 0, 0);
        acc[1][nt] = __builtin_amdgcn_mfma_f32_16x16x32_bf16(af1, bf, acc[1][nt], 0, 0, 0);
      }
    }
    // pool over 32 rows: in-lane 8 values, then xor 16/32 across row groups
#pragma unroll
    for (int nt = 0; nt < 4; ++nt) {
      float m0 = fmaxf(fmaxf(acc[0][nt][0], acc[0][nt][1]),
                       fmaxf(acc[0][nt][2], acc[0][nt][3]));
      float m1 = fmaxf(fmaxf(acc[1][nt][0], acc[1][nt][1]),
                       fmaxf(acc[1][nt][2], acc[1][nt][3]));
      float m = fmaxf(m0, m1);
      m = fmaxf(m, __shfl_xor(m, 16));
      m = fmaxf(m, __shfl_xor(m, 32));
      if (gq == 0) og[64*h + 16*nt + c] = m;
    }
  }
}

// ---------------------------------------------------------------------------
extern "C" void kernel_launch(void* const* d_in, const int* in_sizes, int n_in,
                              void* d_out, int out_size, void* d_ws, size_t ws_size,
                              hipStream_t stream)
{
  const float* xyz  = (const float*)d_in[0];
  const float* feat = (const float*)d_in[1];
  const float* W1   = (const float*)d_in[2];
  const float* b1   = (const float*)d_in[3];
  const float* g1   = (const float*)d_in[4];
  const float* be1  = (const float*)d_in[5];
  const float* W2   = (const float*)d_in[6];
  const float* b2   = (const float*)d_in[7];
  const float* g2   = (const float*)d_in[8];
  const float* be2  = (const float*)d_in[9];
  const float* Wout = (const float*)d_in[10];
  const float* bout = (const float*)d_in[11];

  float* outp = (float*)d_out;
  float* cent = outp;                             // (B, M, 3)
  float* o    = outp + (size_t)Bn * Mn * 3;       // (B, M, 128)

  fps_kernel<<<Bn, 256, 0, stream>>>(xyz, cent);
  knn_kernel<<<Bn * Mn / 4, 256, 0, stream>>>(xyz, cent, (int*)o);
  mlp_kernel<<<Bn * Mn / 4, 256, 0, stream>>>(xyz, feat,
                                              W1, b1, g1, be1,
                                              W2, b2, g2, be2,
                                              Wout, bout, cent, o);
}

// Round 17
// 1031.041 us; speedup vs baseline: 2.5653x; 1.0453x over previous
//
#include <hip/hip_runtime.h>
#include <math.h>

#define Bn   16
#define Nn   4096
#define Cn   64
#define Mn   1024
#define Kn   32
#define OUTn 128
#define EPS  1e-5f

typedef unsigned long long u64;
typedef unsigned int u32;
typedef unsigned short u16;
typedef __attribute__((ext_vector_type(8))) short bf16x8;
typedef __attribute__((ext_vector_type(4))) float f32x4;

__device__ __forceinline__ u64 u64min(u64 a, u64 b) { return a < b ? a : b; }
__device__ __forceinline__ u64 u64max(u64 a, u64 b) { return a > b ? a : b; }

template<int CTRL>
__device__ __forceinline__ u64 dpp_u64(u64 x) {
  union { u64 q; u32 w[2]; } in, out;
  in.q = x;
  out.w[0] = (u32)__builtin_amdgcn_update_dpp((int)in.w[0], (int)in.w[0], CTRL, 0xf, 0xf, false);
  out.w[1] = (u32)__builtin_amdgcn_update_dpp((int)in.w[1], (int)in.w[1], CTRL, 0xf, 0xf, false);
  return out.q;
}

__device__ __forceinline__ u64 wave_max_dpp(u64 v) {
  v = u64max(v, dpp_u64<0x111>(v));
  v = u64max(v, dpp_u64<0x112>(v));
  v = u64max(v, dpp_u64<0x114>(v));
  v = u64max(v, dpp_u64<0x118>(v));
  v = u64max(v, dpp_u64<0x142>(v));
  v = u64max(v, dpp_u64<0x143>(v));
  return v;
}
__device__ __forceinline__ u64 wave_min_dpp(u64 v) {
  v = u64min(v, dpp_u64<0x111>(v));
  v = u64min(v, dpp_u64<0x112>(v));
  v = u64min(v, dpp_u64<0x114>(v));
  v = u64min(v, dpp_u64<0x118>(v));
  v = u64min(v, dpp_u64<0x142>(v));
  v = u64min(v, dpp_u64<0x143>(v));
  return v;
}

// RTN f32->bf16 pack helpers
__device__ __forceinline__ u32 rnd2(float a, float b) {
  u32 ua = __float_as_uint(a);
  ua = (ua + 0x7FFFu + ((ua >> 16) & 1u)) >> 16;
  u32 ub = __float_as_uint(b);
  ub = (ub + 0x7FFFu + ((ub >> 16) & 1u)) & 0xFFFF0000u;
  return ua | ub;
}
__device__ __forceinline__ u16 bf16s(float a) {
  u32 ua = __float_as_uint(a);
  return (u16)((ua + 0x7FFFu + ((ua >> 16) & 1u)) >> 16);
}

// ---------------------------------------------------------------------------
// Weight pre-conversion: f32 -> bf16 (RTN, identical to r14's in-kernel pack),
// fragment-ready k-order, into d_ws. Layout (bf16 units):
//   [0, 6144)      W1k [64][96]: k<64 -> W1[r][3+k]; 64..66 -> W1[r][k-64]; else 0
//   [6144, 10240)  W2  [64][64]
//   [10240, 18432) Wout[128][64]
// Runs every launch (~2us); fully rewrites before mlp reads -> deterministic.
// ---------------------------------------------------------------------------
__global__ __launch_bounds__(256) void wconv_kernel(
    const float* __restrict__ W1, const float* __restrict__ W2,
    const float* __restrict__ Wout, u16* __restrict__ wb)
{
  const int i = blockIdx.x * 256 + threadIdx.x;   // 0 .. 18431
  float v;
  if (i < 6144) {
    const int r = i / 96, k = i % 96;
    v = (k < 64) ? W1[r * 67 + 3 + k] : (k < 67 ? W1[r * 67 + (k - 64)] : 0.0f);
  } else if (i < 10240) {
    v = W2[i - 6144];
  } else {
    v = Wout[i - 10240];
  }
  wb[i] = bf16s(v);
}

// ---------------------------------------------------------------------------
// FPS: r13 version, byte-identical (best measured: 647 us).
// ---------------------------------------------------------------------------
__global__ __launch_bounds__(256) void fps_kernel(
    const float* __restrict__ xyz, float* __restrict__ cent)
{
  __shared__ float4 pts4[Nn];          // 64 KB
  __shared__ __align__(16) u64 pvq[2][4];

  const int b = blockIdx.x;
  const int t = threadIdx.x;
  const float* src = xyz + (size_t)b * Nn * 3;

  for (int i = t; i < Nn; i += 256) {
    pts4[i] = make_float4(src[3*i+0], src[3*i+1], src[3*i+2], 0.0f);
  }
  __syncthreads();

  const float4 c0 = pts4[0];

  float px[16], py[16], pz[16], d[16];
  u32 ninv[16];
#pragma unroll
  for (int j = 0; j < 16; ++j) {
    const int n = j * 256 + t;
    ninv[j] = (u32)(~n);
    const float4 p = pts4[n];
    px[j] = p.x; py[j] = p.y; pz[j] = p.z;
    const float dx = px[j] - c0.x, dy = py[j] - c0.y, dz = pz[j] - c0.z;
    d[j] = (dx * dx + dy * dy) + dz * dz;
  }

  if (t == 0) {
    float* o = cent + (size_t)b * Mn * 3;
    o[0] = c0.x; o[1] = c0.y; o[2] = c0.z;
  }

  for (int m = 1; m < Mn; ++m) {
    u64 k[16];
#pragma unroll
    for (int j = 0; j < 16; ++j)
      k[j] = ((u64)__float_as_uint(d[j]) << 32) | ninv[j];
#pragma unroll
    for (int st = 1; st < 16; st <<= 1)
#pragma unroll
      for (int j = 0; j < 16; j += (st << 1))
        k[j] = u64max(k[j], k[j + st]);

    const u64 bk = wave_max_dpp(k[0]);
    const int par = m & 1;
    if ((t & 63) == 63) pvq[par][t >> 6] = bk;
    __syncthreads();

    const u64 f = u64max(u64max(pvq[par][0], pvq[par][1]),
                         u64max(pvq[par][2], pvq[par][3]));
    const int fi = (int)(~(u32)f);

    const float4 cp = pts4[fi];
    if (t == 0) {
      float* o = cent + ((size_t)b * Mn + m) * 3;
      o[0] = cp.x; o[1] = cp.y; o[2] = cp.z;
    }

#pragma unroll
    for (int j = 0; j < 16; ++j) {
      const float dx = px[j] - cp.x, dy = py[j] - cp.y, dz = pz[j] - cp.z;
      const float nd = (dx * dx + dy * dy) + dz * dz;
      d[j] = fminf(d[j], nd);
    }
  }
}

// ---------------------------------------------------------------------------
// KNN: r13 version, byte-identical (one wave/centroid, zero LDS/barriers).
// ---------------------------------------------------------------------------
__global__ __launch_bounds__(256) void knn_kernel(
    const float* __restrict__ xyz, const float* __restrict__ cent,
    int* __restrict__ osel)
{
  const int t    = threadIdx.x;
  const int lane = t & 63;
  const int wid  = __builtin_amdgcn_readfirstlane(t >> 6);
  const int g    = (blockIdx.x << 2) + wid;
  const int b    = g >> 10;
  const float* P = xyz + (size_t)b * Nn * 3;

  const float cx = cent[(size_t)g * 3 + 0];
  const float cy = cent[(size_t)g * 3 + 1];
  const float cz = cent[(size_t)g * 3 + 2];
  const float cc2 = (cx * cx + cy * cy) + cz * cz;

  u64 kk[4][16];
  u64 gm0, gm1, gm2, gm3;

#pragma unroll
  for (int grp = 0; grp < 4; ++grp) {
#pragma unroll
    for (int j = 0; j < 16; ++j) {
      const int n = grp * 1024 + j * 64 + lane;
      const float x = P[n*3+0], y = P[n*3+1], z = P[n*3+2];
      const float pp = (x * x + y * y) + z * z;
      const float dt = (cx * x + cy * y) + cz * z;
      const float d2 = (cc2 + pp) - 2.0f * dt;
      const u32 bu = __float_as_uint(d2);
      const u32 mo = bu ^ (0x80000000u | (u32)((int)bu >> 31));
      kk[grp][j] = ((u64)mo << 32) | (u32)n;
    }
  }
#define TREE16(dst, A_)                                                 \
  {                                                                     \
    u64 t0 = u64min(A_[0], A_[1]),  t1 = u64min(A_[2], A_[3]);          \
    u64 t2 = u64min(A_[4], A_[5]),  t3 = u64min(A_[6], A_[7]);          \
    u64 t4 = u64min(A_[8], A_[9]),  t5 = u64min(A_[10], A_[11]);        \
    u64 t6 = u64min(A_[12], A_[13]), t7 = u64min(A_[14], A_[15]);       \
    t0 = u64min(t0, t1); t2 = u64min(t2, t3);                           \
    t4 = u64min(t4, t5); t6 = u64min(t6, t7);                           \
    dst = u64min(u64min(t0, t2), u64min(t4, t6));                       \
  }
  TREE16(gm0, kk[0]); TREE16(gm1, kk[1]);
  TREE16(gm2, kk[2]); TREE16(gm3, kk[3]);
  u64 bk = u64min(u64min(gm0, gm1), u64min(gm2, gm3));

  int myfi = 0;
  for (int s = 0; s < Kn; ++s) {
    const u64 v = wave_min_dpp(bk);
    const u32 flo = (u32)__builtin_amdgcn_readlane((int)(u32)v, 63);
    const int fi = (int)flo;
    if (lane == s) myfi = fi;

    const int og = __builtin_amdgcn_readfirstlane(fi >> 10);
    const int oj = __builtin_amdgcn_readfirstlane((fi >> 6) & 15);
    if (lane == (fi & 63)) {
#pragma unroll
      for (int grp = 0; grp < 4; ++grp) {
        if (grp == og) {
#pragma unroll
          for (int j = 0; j < 16; ++j)
            if (j == oj) kk[grp][j] = ~0ull;
          u64 nm;
          TREE16(nm, kk[grp]);
          if (grp == 0) gm0 = nm;
          else if (grp == 1) gm1 = nm;
          else if (grp == 2) gm2 = nm;
          else gm3 = nm;
        }
      }
      bk = u64min(u64min(gm0, gm1), u64min(gm2, gm3));
    }
  }
#undef TREE16

  if (lane < Kn) osel[(size_t)g * 128 + lane] = myfi;
}

// ---------------------------------------------------------------------------
// MLP via bf16 MFMA, weights PRE-CONVERTED (wconv) -> per-fragment load is
// ONE 16B dwordx4 from L2-resident bf16, zero pack VALU. One block per 4
// centroids; wave w owns centroid w (32 rows x 64 cols): LN + maxpool fully
// in-wave, ONE barrier total. X staged bf16 in LDS [128][104] (stride 52
// dwords). L1 is now 3 uniform ks-steps (coord weights live in the wconv
// layout at k=64..66). Fragment layouts: A row=l&15, k=8*(l>>4)+e; B col=l&15
// same k; C/D col=l&15, row=4*(l>>4)+reg (verified r14, absmax 0.03125).
// ---------------------------------------------------------------------------
__global__ __launch_bounds__(256) void mlp_kernel(
    const float* __restrict__ xyz, const float* __restrict__ feat,
    const u16* __restrict__ wb,
    const float* __restrict__ b1, const float* __restrict__ g1,
    const float* __restrict__ be1,
    const float* __restrict__ b2, const float* __restrict__ g2,
    const float* __restrict__ be2, const float* __restrict__ bout,
    const float* __restrict__ cent, float* __restrict__ out)
{
  __shared__ u32 Xw[128][52];        // 128 rows x 104 bf16 (26.6 KB)

  const int g0   = blockIdx.x << 2;
  const int b    = g0 >> 10;
  const int t    = threadIdx.x;
  const int wid  = __builtin_amdgcn_readfirstlane(t >> 6);
  const int lane = t & 63;

  const float* P = xyz  + (size_t)b * Nn * 3;
  const float* F = feat + (size_t)b * Nn * Cn;
  const int* osel = (const int*)out;

  const u16* w1b = wb;               // [64][96]
  const u16* w2b = wb + 6144;        // [64][64]
  const u16* w3b = wb + 10240;       // [128][64]

  // ---- gather -> bf16 LDS (2 threads per row) ----
  {
    const int row = t >> 1, half = t & 1;
    const int gi = g0 + (row >> 5);
    const int n = osel[(size_t)gi * 128 + (row & 31)];
    const float* fr = F + (size_t)n * Cn + 32 * half;
#pragma unroll
    for (int q = 0; q < 4; ++q) {
      const float4 a = ((const float4*)fr)[2*q];
      const float4 c = ((const float4*)fr)[2*q+1];
      uint4 wv;
      wv.x = rnd2(a.x, a.y); wv.y = rnd2(a.z, a.w);
      wv.z = rnd2(c.x, c.y); wv.w = rnd2(c.z, c.w);
      *(uint4*)&Xw[row][16*half + 4*q] = wv;
    }
    if (half) {
      const float pxc = P[n*3+0] - cent[(size_t)gi*3+0];
      const float pyc = P[n*3+1] - cent[(size_t)gi*3+1];
      const float pzc = P[n*3+2] - cent[(size_t)gi*3+2];
      Xw[row][32] = rnd2(pxc, pyc);
      Xw[row][33] = rnd2(pzc, 0.0f);
      Xw[row][34] = 0; Xw[row][35] = 0;
#pragma unroll
      for (int q2 = 0; q2 < 4; ++q2) {
        uint4 z; z.x = z.y = z.z = z.w = 0;
        *(uint4*)&Xw[row][36 + 4*q2] = z;
      }
    }
  }
  __syncthreads();

  const int c  = lane & 15;          // frag col / A-row low
  const int gq = lane >> 4;          // frag k-group / C-row group
  const int R0 = wid << 5;           // wave's first row (centroid wid)
  const short* xs_base = (const short*)Xw;

  f32x4 acc[2][4];

  // ================= layer 1: K=96 (feats | coords | pad) ==============
#pragma unroll
  for (int nt = 0; nt < 4; ++nt) {
    const float bv = b1[16*nt + c];
    acc[0][nt] = (f32x4){bv, bv, bv, bv};
    acc[1][nt] = (f32x4){bv, bv, bv, bv};
  }
#pragma unroll
  for (int ks = 0; ks < 3; ++ks) {
    const bf16x8 af0 = *(const bf16x8*)(xs_base + (R0 +      c) * 104 + 32*ks + 8*gq);
    const bf16x8 af1 = *(const bf16x8*)(xs_base + (R0 + 16 + c) * 104 + 32*ks + 8*gq);
#pragma unroll
    for (int nt = 0; nt < 4; ++nt) {
      const bf16x8 bf = *(const bf16x8*)(w1b + (16*nt + c) * 96 + 32*ks + 8*gq);
      acc[0][nt] = __builtin_amdgcn_mfma_f32_16x16x32_bf16(af0, bf, acc[0][nt], 0, 0, 0);
      acc[1][nt] = __builtin_amdgcn_mfma_f32_16x16x32_bf16(af1, bf, acc[1][nt], 0, 0, 0);
    }
  }

  // ---- LN1 + ReLU (in-wave) -> Xw bf16 cols 0..63 ----
  {
    float gg[4], bb[4];
#pragma unroll
    for (int nt = 0; nt < 4; ++nt) { gg[nt] = g1[16*nt + c]; bb[nt] = be1[16*nt + c]; }
#pragma unroll
    for (int mt = 0; mt < 2; ++mt) {
#pragma unroll
      for (int r = 0; r < 4; ++r) {
        const float v0 = acc[mt][0][r], v1 = acc[mt][1][r];
        const float v2 = acc[mt][2][r], v3 = acc[mt][3][r];
        float s = (v0 + v1) + (v2 + v3);
        float q = fmaf(v0, v0, fmaf(v1, v1, fmaf(v2, v2, v3 * v3)));
#pragma unroll
        for (int off = 1; off < 16; off <<= 1) {
          s += __shfl_xor(s, off);
          q += __shfl_xor(q, off);
        }
        const float mu = s * 0.015625f;
        const float var = q * 0.015625f - mu * mu;
        const float rs = rsqrtf(var + EPS);
        const int row = R0 + 16*mt + 4*gq + r;
        short* xsw = (short*)Xw + row * 104;
#pragma unroll
        for (int nt = 0; nt < 4; ++nt) {
          const float y = fmaxf((acc[mt][nt][r] - mu) * rs * gg[nt] + bb[nt], 0.0f);
          xsw[16*nt + c] = (short)bf16s(y);
        }
      }
    }
  }

  // ================= layer 2: K=64 =================
#pragma unroll
  for (int nt = 0; nt < 4; ++nt) {
    const float bv = b2[16*nt + c];
    acc[0][nt] = (f32x4){bv, bv, bv, bv};
    acc[1][nt] = (f32x4){bv, bv, bv, bv};
  }
#pragma unroll
  for (int ks = 0; ks < 2; ++ks) {
    const bf16x8 af0 = *(const bf16x8*)(xs_base + (R0 +      c) * 104 + 32*ks + 8*gq);
    const bf16x8 af1 = *(const bf16x8*)(xs_base + (R0 + 16 + c) * 104 + 32*ks + 8*gq);
#pragma unroll
    for (int nt = 0; nt < 4; ++nt) {
      const bf16x8 bf = *(const bf16x8*)(w2b + (16*nt + c) * 64 + 32*ks + 8*gq);
      acc[0][nt] = __builtin_amdgcn_mfma_f32_16x16x32_bf16(af0, bf, acc[0][nt], 0, 0, 0);
      acc[1][nt] = __builtin_amdgcn_mfma_f32_16x16x32_bf16(af1, bf, acc[1][nt], 0, 0, 0);
    }
  }

  // ---- LN2 + ReLU (in-wave) -> Xw bf16 cols 0..63 ----
  {
    float gg[4], bb[4];
#pragma unroll
    for (int nt = 0; nt < 4; ++nt) { gg[nt] = g2[16*nt + c]; bb[nt] = be2[16*nt + c]; }
#pragma unroll
    for (int mt = 0; mt < 2; ++mt) {
#pragma unroll
      for (int r = 0; r < 4; ++r) {
        const float v0 = acc[mt][0][r], v1 = acc[mt][1][r];
        const float v2 = acc[mt][2][r], v3 = acc[mt][3][r];
        float s = (v0 + v1) + (v2 + v3);
        float q = fmaf(v0, v0, fmaf(v1, v1, fmaf(v2, v2, v3 * v3)));
#pragma unroll
        for (int off = 1; off < 16; off <<= 1) {
          s += __shfl_xor(s, off);
          q += __shfl_xor(q, off);
        }
        const float mu = s * 0.015625f;
        const float var = q * 0.015625f - mu * mu;
        const float rs = rsqrtf(var + EPS);
        const int row = R0 + 16*mt + 4*gq + r;
        short* xsw = (short*)Xw + row * 104;
#pragma unroll
        for (int nt = 0; nt < 4; ++nt) {
          const float y = fmaxf((acc[mt][nt][r] - mu) * rs * gg[nt] + bb[nt], 0.0f);
          xsw[16*nt + c] = (short)bf16s(y);
        }
      }
    }
  }

  // ================= layer 3: N=128 in two 64-col halves + maxpool =======
  float* og = out + (size_t)(g0 + wid) * OUTn;
#pragma unroll
  for (int h = 0; h < 2; ++h) {
#pragma unroll
    for (int nt = 0; nt < 4; ++nt) {
      const float bv = bout[64*h + 16*nt + c];
      acc[0][nt] = (f32x4){bv, bv, bv, bv};
      acc[1][nt] = (f32x4){bv, bv, bv, bv};
    }
#pragma unroll
    for (int ks = 0; ks < 2; ++ks) {
      const bf16x8 af0 = *(const bf16x8*)(xs_base + (R0 +      c) * 104 + 32*ks + 8*gq);
      const bf16x8 af1 = *(const bf16x8*)(xs_base + (R0 + 16 + c) * 104 + 32*ks + 8*gq);
#pragma unroll
      for (int nt = 0; nt < 4; ++nt) {
        const bf16x8 bf = *(const bf16x8*)(w3b + (size_t)(64*h + 16*nt + c) * 64 + 32*ks + 8*gq);
        acc[0][nt] = __builtin_amdgcn_mfma_f32_16x16x32_bf16(af0, bf, acc[0][nt], 0, 0, 0);
        acc[1][nt] = __builtin_amdgcn_mfma_f32_16x16x32_bf16(af1, bf, acc[1][nt], 0, 0, 0);
      }
    }
#pragma unroll
    for (int nt = 0; nt < 4; ++nt) {
      float m0 = fmaxf(fmaxf(acc[0][nt][0], acc[0][nt][1]),
                       fmaxf(acc[0][nt][2], acc[0][nt][3]));
      float m1 = fmaxf(fmaxf(acc[1][nt][0], acc[1][nt][1]),
                       fmaxf(acc[1][nt][2], acc[1][nt][3]));
      float m = fmaxf(m0, m1);
      m = fmaxf(m, __shfl_xor(m, 16));
      m = fmaxf(m, __shfl_xor(m, 32));
      if (gq == 0) og[64*h + 16*nt + c] = m;
    }
  }
}

// ---------------------------------------------------------------------------
extern "C" void kernel_launch(void* const* d_in, const int* in_sizes, int n_in,
                              void* d_out, int out_size, void* d_ws, size_t ws_size,
                              hipStream_t stream)
{
  const float* xyz  = (const float*)d_in[0];
  const float* feat = (const float*)d_in[1];
  const float* W1   = (const float*)d_in[2];
  const float* b1   = (const float*)d_in[3];
  const float* g1   = (const float*)d_in[4];
  const float* be1  = (const float*)d_in[5];
  const float* W2   = (const float*)d_in[6];
  const float* b2   = (const float*)d_in[7];
  const float* g2   = (const float*)d_in[8];
  const float* be2  = (const float*)d_in[9];
  const float* Wout = (const float*)d_in[10];
  const float* bout = (const float*)d_in[11];

  float* outp = (float*)d_out;
  float* cent = outp;                             // (B, M, 3)
  float* o    = outp + (size_t)Bn * Mn * 3;       // (B, M, 128)
  u16*   wb   = (u16*)d_ws;                       // 18432 bf16 = 36.9 KB

  wconv_kernel<<<72, 256, 0, stream>>>(W1, W2, Wout, wb);
  fps_kernel<<<Bn, 256, 0, stream>>>(xyz, cent);
  knn_kernel<<<Bn * Mn / 4, 256, 0, stream>>>(xyz, cent, (int*)o);
  mlp_kernel<<<Bn * Mn / 4, 256, 0, stream>>>(xyz, feat, wb,
                                              b1, g1, be1,
                                              b2, g2, be2, bout,
                                              cent, o);
}

// Round 18
// 913.700 us; speedup vs baseline: 2.8948x; 1.1284x over previous
//
#include <hip/hip_runtime.h>
#include <math.h>

#define Bn   16
#define Nn   4096
#define Cn   64
#define Mn   1024
#define Kn   32
#define OUTn 128
#define EPS  1e-5f

typedef unsigned long long u64;
typedef unsigned int u32;
typedef unsigned short u16;
typedef __attribute__((ext_vector_type(8))) short bf16x8;
typedef __attribute__((ext_vector_type(4))) float f32x4;

__device__ __forceinline__ u64 u64min(u64 a, u64 b) { return a < b ? a : b; }
__device__ __forceinline__ u64 u64max(u64 a, u64 b) { return a > b ? a : b; }

template<int CTRL>
__device__ __forceinline__ u64 dpp_u64(u64 x) {
  union { u64 q; u32 w[2]; } in, out;
  in.q = x;
  out.w[0] = (u32)__builtin_amdgcn_update_dpp((int)in.w[0], (int)in.w[0], CTRL, 0xf, 0xf, false);
  out.w[1] = (u32)__builtin_amdgcn_update_dpp((int)in.w[1], (int)in.w[1], CTRL, 0xf, 0xf, false);
  return out.q;
}
// f32 DPP move (old = x, full masks). row_ror:N = 0x120|N operates within
// 16-lane rows -> rotation allreduce for our 16-lane LN groups.
template<int CTRL>
__device__ __forceinline__ float dpp_f32(float x) {
  return __uint_as_float((u32)__builtin_amdgcn_update_dpp(
      (int)__float_as_uint(x), (int)__float_as_uint(x), CTRL, 0xf, 0xf, false));
}

__device__ __forceinline__ u64 wave_max_dpp(u64 v) {
  v = u64max(v, dpp_u64<0x111>(v));
  v = u64max(v, dpp_u64<0x112>(v));
  v = u64max(v, dpp_u64<0x114>(v));
  v = u64max(v, dpp_u64<0x118>(v));
  v = u64max(v, dpp_u64<0x142>(v));
  v = u64max(v, dpp_u64<0x143>(v));
  return v;
}
__device__ __forceinline__ u64 wave_min_dpp(u64 v) {
  v = u64min(v, dpp_u64<0x111>(v));
  v = u64min(v, dpp_u64<0x112>(v));
  v = u64min(v, dpp_u64<0x114>(v));
  v = u64min(v, dpp_u64<0x118>(v));
  v = u64min(v, dpp_u64<0x142>(v));
  v = u64min(v, dpp_u64<0x143>(v));
  return v;
}

// RTN f32->bf16 pack helpers
__device__ __forceinline__ u32 rnd2(float a, float b) {
  u32 ua = __float_as_uint(a);
  ua = (ua + 0x7FFFu + ((ua >> 16) & 1u)) >> 16;
  u32 ub = __float_as_uint(b);
  ub = (ub + 0x7FFFu + ((ub >> 16) & 1u)) & 0xFFFF0000u;
  return ua | ub;
}
__device__ __forceinline__ u16 bf16s(float a) {
  u32 ua = __float_as_uint(a);
  return (u16)((ua + 0x7FFFu + ((ua >> 16) & 1u)) >> 16);
}

// ---------------------------------------------------------------------------
// Weight pre-conversion (r17, unchanged): f32 -> bf16 RTN, fragment k-order.
// ---------------------------------------------------------------------------
__global__ __launch_bounds__(256) void wconv_kernel(
    const float* __restrict__ W1, const float* __restrict__ W2,
    const float* __restrict__ Wout, u16* __restrict__ wb)
{
  const int i = blockIdx.x * 256 + threadIdx.x;   // 0 .. 18431
  float v;
  if (i < 6144) {
    const int r = i / 96, k = i % 96;
    v = (k < 64) ? W1[r * 67 + 3 + k] : (k < 67 ? W1[r * 67 + (k - 64)] : 0.0f);
  } else if (i < 10240) {
    v = W2[i - 6144];
  } else {
    v = Wout[i - 10240];
  }
  wb[i] = bf16s(v);
}

// ---------------------------------------------------------------------------
// Point pre-pack: xyz (B,N,3) -> float4 array in ws. Exact copies (no
// rounding) -> knn keys bit-identical; loads become coalesced dwordx4.
// ---------------------------------------------------------------------------
__global__ __launch_bounds__(256) void pconv_kernel(
    const float* __restrict__ xyz, float4* __restrict__ p4)
{
  const int i = blockIdx.x * 256 + threadIdx.x;   // 0 .. 65535
  p4[i] = make_float4(xyz[3*i+0], xyz[3*i+1], xyz[3*i+2], 0.0f);
}

// ---------------------------------------------------------------------------
// FPS: r13 version, byte-identical (best measured: 647 us; restructure
// attempts r7/r8/r11 all regressed -> this is the measured floor).
// ---------------------------------------------------------------------------
__global__ __launch_bounds__(256) void fps_kernel(
    const float* __restrict__ xyz, float* __restrict__ cent)
{
  __shared__ float4 pts4[Nn];          // 64 KB
  __shared__ __align__(16) u64 pvq[2][4];

  const int b = blockIdx.x;
  const int t = threadIdx.x;
  const float* src = xyz + (size_t)b * Nn * 3;

  for (int i = t; i < Nn; i += 256) {
    pts4[i] = make_float4(src[3*i+0], src[3*i+1], src[3*i+2], 0.0f);
  }
  __syncthreads();

  const float4 c0 = pts4[0];

  float px[16], py[16], pz[16], d[16];
  u32 ninv[16];
#pragma unroll
  for (int j = 0; j < 16; ++j) {
    const int n = j * 256 + t;
    ninv[j] = (u32)(~n);
    const float4 p = pts4[n];
    px[j] = p.x; py[j] = p.y; pz[j] = p.z;
    const float dx = px[j] - c0.x, dy = py[j] - c0.y, dz = pz[j] - c0.z;
    d[j] = (dx * dx + dy * dy) + dz * dz;
  }

  if (t == 0) {
    float* o = cent + (size_t)b * Mn * 3;
    o[0] = c0.x; o[1] = c0.y; o[2] = c0.z;
  }

  for (int m = 1; m < Mn; ++m) {
    u64 k[16];
#pragma unroll
    for (int j = 0; j < 16; ++j)
      k[j] = ((u64)__float_as_uint(d[j]) << 32) | ninv[j];
#pragma unroll
    for (int st = 1; st < 16; st <<= 1)
#pragma unroll
      for (int j = 0; j < 16; j += (st << 1))
        k[j] = u64max(k[j], k[j + st]);

    const u64 bk = wave_max_dpp(k[0]);
    const int par = m & 1;
    if ((t & 63) == 63) pvq[par][t >> 6] = bk;
    __syncthreads();

    const u64 f = u64max(u64max(pvq[par][0], pvq[par][1]),
                         u64max(pvq[par][2], pvq[par][3]));
    const int fi = (int)(~(u32)f);

    const float4 cp = pts4[fi];
    if (t == 0) {
      float* o = cent + ((size_t)b * Mn + m) * 3;
      o[0] = cp.x; o[1] = cp.y; o[2] = cp.z;
    }

#pragma unroll
    for (int j = 0; j < 16; ++j) {
      const float dx = px[j] - cp.x, dy = py[j] - cp.y, dz = pz[j] - cp.z;
      const float nd = (dx * dx + dy * dy) + dz * dz;
      d[j] = fminf(d[j], nd);
    }
  }
}

// ---------------------------------------------------------------------------
// KNN core (templated on point source). One wave per centroid, zero LDS,
// zero barriers. Keys (mono(bits(d2))<<32)|n; u64 MIN == stable top_k set.
// ---------------------------------------------------------------------------
template<bool USE_P4>
__device__ __forceinline__ void knn_body(
    const float* __restrict__ P, const float4* __restrict__ P4,
    const float* __restrict__ cent, int* __restrict__ osel,
    int g, int lane)
{
  const float cx = cent[(size_t)g * 3 + 0];
  const float cy = cent[(size_t)g * 3 + 1];
  const float cz = cent[(size_t)g * 3 + 2];
  const float cc2 = (cx * cx + cy * cy) + cz * cz;

  u64 kk[4][16];
  u64 gm0, gm1, gm2, gm3;

#pragma unroll
  for (int grp = 0; grp < 4; ++grp) {
#pragma unroll
    for (int j = 0; j < 16; ++j) {
      const int n = grp * 1024 + j * 64 + lane;
      float x, y, z;
      if (USE_P4) {
        const float4 p = P4[n];
        x = p.x; y = p.y; z = p.z;
      } else {
        x = P[n*3+0]; y = P[n*3+1]; z = P[n*3+2];
      }
      const float pp = (x * x + y * y) + z * z;
      const float dt = (cx * x + cy * y) + cz * z;
      const float d2 = (cc2 + pp) - 2.0f * dt;
      const u32 bu = __float_as_uint(d2);
      const u32 mo = bu ^ (0x80000000u | (u32)((int)bu >> 31));
      kk[grp][j] = ((u64)mo << 32) | (u32)n;
    }
  }
#define TREE16(dst, A_)                                                 \
  {                                                                     \
    u64 t0 = u64min(A_[0], A_[1]),  t1 = u64min(A_[2], A_[3]);          \
    u64 t2 = u64min(A_[4], A_[5]),  t3 = u64min(A_[6], A_[7]);          \
    u64 t4 = u64min(A_[8], A_[9]),  t5 = u64min(A_[10], A_[11]);        \
    u64 t6 = u64min(A_[12], A_[13]), t7 = u64min(A_[14], A_[15]);       \
    t0 = u64min(t0, t1); t2 = u64min(t2, t3);                           \
    t4 = u64min(t4, t5); t6 = u64min(t6, t7);                           \
    dst = u64min(u64min(t0, t2), u64min(t4, t6));                       \
  }
  TREE16(gm0, kk[0]); TREE16(gm1, kk[1]);
  TREE16(gm2, kk[2]); TREE16(gm3, kk[3]);
  u64 bk = u64min(u64min(gm0, gm1), u64min(gm2, gm3));

  int myfi = 0;
  for (int s = 0; s < Kn; ++s) {
    const u64 v = wave_min_dpp(bk);
    const u32 flo = (u32)__builtin_amdgcn_readlane((int)(u32)v, 63);
    const int fi = (int)flo;
    if (lane == s) myfi = fi;

    const int og = __builtin_amdgcn_readfirstlane(fi >> 10);
    const int oj = __builtin_amdgcn_readfirstlane((fi >> 6) & 15);
    if (lane == (fi & 63)) {
#pragma unroll
      for (int grp = 0; grp < 4; ++grp) {
        if (grp == og) {
#pragma unroll
          for (int j = 0; j < 16; ++j)
            if (j == oj) kk[grp][j] = ~0ull;
          u64 nm;
          TREE16(nm, kk[grp]);
          if (grp == 0) gm0 = nm;
          else if (grp == 1) gm1 = nm;
          else if (grp == 2) gm2 = nm;
          else gm3 = nm;
        }
      }
      bk = u64min(u64min(gm0, gm1), u64min(gm2, gm3));
    }
  }
#undef TREE16

  if (lane < Kn) osel[(size_t)g * 128 + lane] = myfi;
}

__global__ __launch_bounds__(256) void knn_kernel(
    const float* __restrict__ xyz, const float* __restrict__ cent,
    int* __restrict__ osel)
{
  const int t    = threadIdx.x;
  const int lane = t & 63;
  const int wid  = __builtin_amdgcn_readfirstlane(t >> 6);
  const int g    = (blockIdx.x << 2) + wid;
  const int b    = g >> 10;
  knn_body<false>(xyz + (size_t)b * Nn * 3, nullptr, cent, osel, g, lane);
}

__global__ __launch_bounds__(256) void knn4_kernel(
    const float4* __restrict__ p4, const float* __restrict__ cent,
    int* __restrict__ osel)
{
  const int t    = threadIdx.x;
  const int lane = t & 63;
  const int wid  = __builtin_amdgcn_readfirstlane(t >> 6);
  const int g    = (blockIdx.x << 2) + wid;
  const int b    = g >> 10;
  knn_body<true>(nullptr, p4 + (size_t)b * Nn, cent, osel, g, lane);
}

// ---------------------------------------------------------------------------
// MLP via bf16 MFMA (r17 structure). Change: LN 16-lane reductions now use
// DPP rotation-allreduce (row_ror 8/4/2/1 -> v_add_f32_dpp, every lane ends
// with the 16-sum) instead of 8 shfl_xor (ds_bpermute) -> ~40% fewer LN
// instructions. Per-lane sum association differs by ulps only (tolerance
// budget 0.099; selection logic untouched).
// ---------------------------------------------------------------------------
__global__ __launch_bounds__(256) void mlp_kernel(
    const float* __restrict__ xyz, const float* __restrict__ feat,
    const u16* __restrict__ wb,
    const float* __restrict__ b1, const float* __restrict__ g1,
    const float* __restrict__ be1,
    const float* __restrict__ b2, const float* __restrict__ g2,
    const float* __restrict__ be2, const float* __restrict__ bout,
    const float* __restrict__ cent, float* __restrict__ out)
{
  __shared__ u32 Xw[128][52];        // 128 rows x 104 bf16 (26.6 KB)

  const int g0   = blockIdx.x << 2;
  const int b    = g0 >> 10;
  const int t    = threadIdx.x;
  const int wid  = __builtin_amdgcn_readfirstlane(t >> 6);
  const int lane = t & 63;

  const float* P = xyz  + (size_t)b * Nn * 3;
  const float* F = feat + (size_t)b * Nn * Cn;
  const int* osel = (const int*)out;

  const u16* w1b = wb;               // [64][96]
  const u16* w2b = wb + 6144;        // [64][64]
  const u16* w3b = wb + 10240;       // [128][64]

  // ---- gather -> bf16 LDS (2 threads per row) ----
  {
    const int row = t >> 1, half = t & 1;
    const int gi = g0 + (row >> 5);
    const int n = osel[(size_t)gi * 128 + (row & 31)];
    const float* fr = F + (size_t)n * Cn + 32 * half;
#pragma unroll
    for (int q = 0; q < 4; ++q) {
      const float4 a = ((const float4*)fr)[2*q];
      const float4 c = ((const float4*)fr)[2*q+1];
      uint4 wv;
      wv.x = rnd2(a.x, a.y); wv.y = rnd2(a.z, a.w);
      wv.z = rnd2(c.x, c.y); wv.w = rnd2(c.z, c.w);
      *(uint4*)&Xw[row][16*half + 4*q] = wv;
    }
    if (half) {
      const float pxc = P[n*3+0] - cent[(size_t)gi*3+0];
      const float pyc = P[n*3+1] - cent[(size_t)gi*3+1];
      const float pzc = P[n*3+2] - cent[(size_t)gi*3+2];
      Xw[row][32] = rnd2(pxc, pyc);
      Xw[row][33] = rnd2(pzc, 0.0f);
      Xw[row][34] = 0; Xw[row][35] = 0;
#pragma unroll
      for (int q2 = 0; q2 < 4; ++q2) {
        uint4 z; z.x = z.y = z.z = z.w = 0;
        *(uint4*)&Xw[row][36 + 4*q2] = z;
      }
    }
  }
  __syncthreads();

  const int c  = lane & 15;          // frag col / A-row low
  const int gq = lane >> 4;          // frag k-group / C-row group
  const int R0 = wid << 5;           // wave's first row (centroid wid)
  const short* xs_base = (const short*)Xw;

  f32x4 acc[2][4];

  // ================= layer 1: K=96 (feats | coords | pad) ==============
#pragma unroll
  for (int nt = 0; nt < 4; ++nt) {
    const float bv = b1[16*nt + c];
    acc[0][nt] = (f32x4){bv, bv, bv, bv};
    acc[1][nt] = (f32x4){bv, bv, bv, bv};
  }
#pragma unroll
  for (int ks = 0; ks < 3; ++ks) {
    const bf16x8 af0 = *(const bf16x8*)(xs_base + (R0 +      c) * 104 + 32*ks + 8*gq);
    const bf16x8 af1 = *(const bf16x8*)(xs_base + (R0 + 16 + c) * 104 + 32*ks + 8*gq);
#pragma unroll
    for (int nt = 0; nt < 4; ++nt) {
      const bf16x8 bf = *(const bf16x8*)(w1b + (16*nt + c) * 96 + 32*ks + 8*gq);
      acc[0][nt] = __builtin_amdgcn_mfma_f32_16x16x32_bf16(af0, bf, acc[0][nt], 0, 0, 0);
      acc[1][nt] = __builtin_amdgcn_mfma_f32_16x16x32_bf16(af1, bf, acc[1][nt], 0, 0, 0);
    }
  }

  // ---- LN1 + ReLU (DPP rotation allreduce) -> Xw bf16 cols 0..63 ----
  {
    float gg[4], bb[4];
#pragma unroll
    for (int nt = 0; nt < 4; ++nt) { gg[nt] = g1[16*nt + c]; bb[nt] = be1[16*nt + c]; }
#pragma unroll
    for (int mt = 0; mt < 2; ++mt) {
#pragma unroll
      for (int r = 0; r < 4; ++r) {
        const float v0 = acc[mt][0][r], v1 = acc[mt][1][r];
        const float v2 = acc[mt][2][r], v3 = acc[mt][3][r];
        float s = (v0 + v1) + (v2 + v3);
        float q = fmaf(v0, v0, fmaf(v1, v1, fmaf(v2, v2, v3 * v3)));
        s += dpp_f32<0x128>(s); q += dpp_f32<0x128>(q);   // row_ror:8
        s += dpp_f32<0x124>(s); q += dpp_f32<0x124>(q);   // row_ror:4
        s += dpp_f32<0x122>(s); q += dpp_f32<0x122>(q);   // row_ror:2
        s += dpp_f32<0x121>(s); q += dpp_f32<0x121>(q);   // row_ror:1
        const float mu = s * 0.015625f;
        const float var = q * 0.015625f - mu * mu;
        const float rs = rsqrtf(var + EPS);
        const int row = R0 + 16*mt + 4*gq + r;
        short* xsw = (short*)Xw + row * 104;
#pragma unroll
        for (int nt = 0; nt < 4; ++nt) {
          const float y = fmaxf((acc[mt][nt][r] - mu) * rs * gg[nt] + bb[nt], 0.0f);
          xsw[16*nt + c] = (short)bf16s(y);
        }
      }
    }
  }

  // ================= layer 2: K=64 =================
#pragma unroll
  for (int nt = 0; nt < 4; ++nt) {
    const float bv = b2[16*nt + c];
    acc[0][nt] = (f32x4){bv, bv, bv, bv};
    acc[1][nt] = (f32x4){bv, bv, bv, bv};
  }
#pragma unroll
  for (int ks = 0; ks < 2; ++ks) {
    const bf16x8 af0 = *(const bf16x8*)(xs_base + (R0 +      c) * 104 + 32*ks + 8*gq);
    const bf16x8 af1 = *(const bf16x8*)(xs_base + (R0 + 16 + c) * 104 + 32*ks + 8*gq);
#pragma unroll
    for (int nt = 0; nt < 4; ++nt) {
      const bf16x8 bf = *(const bf16x8*)(w2b + (16*nt + c) * 64 + 32*ks + 8*gq);
      acc[0][nt] = __builtin_amdgcn_mfma_f32_16x16x32_bf16(af0, bf, acc[0][nt], 0, 0, 0);
      acc[1][nt] = __builtin_amdgcn_mfma_f32_16x16x32_bf16(af1, bf, acc[1][nt], 0, 0, 0);
    }
  }

  // ---- LN2 + ReLU (DPP rotation allreduce) -> Xw bf16 cols 0..63 ----
  {
    float gg[4], bb[4];
#pragma unroll
    for (int nt = 0; nt < 4; ++nt) { gg[nt] = g2[16*nt + c]; bb[nt] = be2[16*nt + c]; }
#pragma unroll
    for (int mt = 0; mt < 2; ++mt) {
#pragma unroll
      for (int r = 0; r < 4; ++r) {
        const float v0 = acc[mt][0][r], v1 = acc[mt][1][r];
        const float v2 = acc[mt][2][r], v3 = acc[mt][3][r];
        float s = (v0 + v1) + (v2 + v3);
        float q = fmaf(v0, v0, fmaf(v1, v1, fmaf(v2, v2, v3 * v3)));
        s += dpp_f32<0x128>(s); q += dpp_f32<0x128>(q);
        s += dpp_f32<0x124>(s); q += dpp_f32<0x124>(q);
        s += dpp_f32<0x122>(s); q += dpp_f32<0x122>(q);
        s += dpp_f32<0x121>(s); q += dpp_f32<0x121>(q);
        const float mu = s * 0.015625f;
        const float var = q * 0.015625f - mu * mu;
        const float rs = rsqrtf(var + EPS);
        const int row = R0 + 16*mt + 4*gq + r;
        short* xsw = (short*)Xw + row * 104;
#pragma unroll
        for (int nt = 0; nt < 4; ++nt) {
          const float y = fmaxf((acc[mt][nt][r] - mu) * rs * gg[nt] + bb[nt], 0.0f);
          xsw[16*nt + c] = (short)bf16s(y);
        }
      }
    }
  }

  // ================= layer 3: N=128 in two 64-col halves + maxpool =======
  float* og = out + (size_t)(g0 + wid) * OUTn;
#pragma unroll
  for (int h = 0; h < 2; ++h) {
#pragma unroll
    for (int nt = 0; nt < 4; ++nt) {
      const float bv = bout[64*h + 16*nt + c];
      acc[0][nt] = (f32x4){bv, bv, bv, bv};
      acc[1][nt] = (f32x4){bv, bv, bv, bv};
    }
#pragma unroll
    for (int ks = 0; ks < 2; ++ks) {
      const bf16x8 af0 = *(const bf16x8*)(xs_base + (R0 +      c) * 104 + 32*ks + 8*gq);
      const bf16x8 af1 = *(const bf16x8*)(xs_base + (R0 + 16 + c) * 104 + 32*ks + 8*gq);
#pragma unroll
      for (int nt = 0; nt < 4; ++nt) {
        const bf16x8 bf = *(const bf16x8*)(w3b + (size_t)(64*h + 16*nt + c) * 64 + 32*ks + 8*gq);
        acc[0][nt] = __builtin_amdgcn_mfma_f32_16x16x32_bf16(af0, bf, acc[0][nt], 0, 0, 0);
        acc[1][nt] = __builtin_amdgcn_mfma_f32_16x16x32_bf16(af1, bf, acc[1][nt], 0, 0, 0);
      }
    }
#pragma unroll
    for (int nt = 0; nt < 4; ++nt) {
      float m0 = fmaxf(fmaxf(acc[0][nt][0], acc[0][nt][1]),
                       fmaxf(acc[0][nt][2], acc[0][nt][3]));
      float m1 = fmaxf(fmaxf(acc[1][nt][0], acc[1][nt][1]),
                       fmaxf(acc[1][nt][2], acc[1][nt][3]));
      float m = fmaxf(m0, m1);
      m = fmaxf(m, __shfl_xor(m, 16));
      m = fmaxf(m, __shfl_xor(m, 32));
      if (gq == 0) og[64*h + 16*nt + c] = m;
    }
  }
}

// ---------------------------------------------------------------------------
extern "C" void kernel_launch(void* const* d_in, const int* in_sizes, int n_in,
                              void* d_out, int out_size, void* d_ws, size_t ws_size,
                              hipStream_t stream)
{
  const float* xyz  = (const float*)d_in[0];
  const float* feat = (const float*)d_in[1];
  const float* W1   = (const float*)d_in[2];
  const float* b1   = (const float*)d_in[3];
  const float* g1   = (const float*)d_in[4];
  const float* be1  = (const float*)d_in[5];
  const float* W2   = (const float*)d_in[6];
  const float* b2   = (const float*)d_in[7];
  const float* g2   = (const float*)d_in[8];
  const float* be2  = (const float*)d_in[9];
  const float* Wout = (const float*)d_in[10];
  const float* bout = (const float*)d_in[11];

  float* outp = (float*)d_out;
  float* cent = outp;                             // (B, M, 3)
  float* o    = outp + (size_t)Bn * Mn * 3;       // (B, M, 128)

  u16*  wb = (u16*)d_ws;                          // 36864 B
  const size_t P4_OFF = 36864;                    // 16B-aligned
  float4* p4 = (float4*)((char*)d_ws + P4_OFF);   // 1 MB
  const bool use_p4 = ws_size >= P4_OFF + (size_t)Bn * Nn * sizeof(float4);

  wconv_kernel<<<72, 256, 0, stream>>>(W1, W2, Wout, wb);
  if (use_p4)
    pconv_kernel<<<Bn * Nn / 256, 256, 0, stream>>>(xyz, p4);
  fps_kernel<<<Bn, 256, 0, stream>>>(xyz, cent);
  if (use_p4)
    knn4_kernel<<<Bn * Mn / 4, 256, 0, stream>>>(p4, cent, (int*)o);
  else
    knn_kernel<<<Bn * Mn / 4, 256, 0, stream>>>(xyz, cent, (int*)o);
  mlp_kernel<<<Bn * Mn / 4, 256, 0, stream>>>(xyz, feat, wb,
                                              b1, g1, be1,
                                              b2, g2, be2, bout,
                                              cent, o);
}